// Round 2
// baseline (2071.314 us; speedup 1.0000x reference)
//
#include <hip/hip_runtime.h>
#include <hip/hip_bf16.h>

#define BB 2
#define CC 256
#define HEADS 8
#define HD 32
#define LL 4096
#define HALF_WIN 512

// ---------------- Kernel 1: QKV projection -----------------------------------
// xt[b,l,c] = x[b,c,l];  qkv[b,l,j] = sum_c xt*w1 + b1[j]
// j factors as j = d*24 + h*3 + t3  ->  q/k/v[b][h][l][d]  (fp32 workspace)
__global__ __launch_bounds__(256) void qkv_kernel(const float* __restrict__ x,
                                                  const float* __restrict__ w1,
                                                  const float* __restrict__ b1,
                                                  float* __restrict__ qw,
                                                  float* __restrict__ kw,
                                                  float* __restrict__ vw) {
    __shared__ float As[64][65];
    __shared__ float Bs[64][65];
    const int j0 = blockIdx.x * 64;
    const int l0 = blockIdx.y * 64;
    const int b  = blockIdx.z;
    const int t  = threadIdx.x;
    const int ll = t & 63;
    const int cog = t >> 6;       // 0..3, wave-uniform
    float acc[16];
#pragma unroll
    for (int k = 0; k < 16; k++) acc[k] = 0.f;

    for (int c0 = 0; c0 < CC; c0 += 64) {
#pragma unroll
        for (int k = 0; k < 16; k++) {
            int idx = k * 256 + t;
            int a_l = idx & 63, a_c = idx >> 6;   // coalesced over l
            As[a_l][a_c] = x[(size_t)b * CC * LL + (size_t)(c0 + a_c) * LL + l0 + a_l];
            int b_r = idx >> 6, b_c = idx & 63;   // coalesced over j
            Bs[b_r][b_c] = w1[(size_t)(c0 + b_r) * 768 + j0 + b_c];
        }
        __syncthreads();
#pragma unroll
        for (int ci = 0; ci < 64; ci++) {
            float a = As[ll][ci];
#pragma unroll
            for (int k = 0; k < 16; k++) acc[k] += a * Bs[ci][cog * 16 + k];
        }
        __syncthreads();
    }

#pragma unroll
    for (int k = 0; k < 16; k++) {
        int j = j0 + cog * 16 + k;
        float val = acc[k] + b1[j];
        int t3 = j % 3;
        int h  = (j / 3) & 7;
        int d  = j / 24;
        float* dst = (t3 == 0) ? qw : (t3 == 1) ? kw : vw;
        dst[(((size_t)b * HEADS + h) * LL + (l0 + ll)) * HD + d] = val;
    }
}

// ---------------- Kernel 2: banded attention ---------------------------------
// One block per (row i, b*heads). Band |i-j|<=512 plus globals {0,63,4032,4095};
// global rows attend to all j.
__global__ __launch_bounds__(256) void attn_kernel(const float* __restrict__ qw,
                                                   const float* __restrict__ kw,
                                                   const float* __restrict__ vw,
                                                   float* __restrict__ obuf) {
    __shared__ float sc[LL];     // 16 KB score/prob buffer, indexed by absolute j
    __shared__ float qs[HD];
    __shared__ float red[256];

    const int i  = blockIdx.x;
    const int bh = blockIdx.y;
    const int t  = threadIdx.x;
    const size_t base = (size_t)bh * LL;

    const bool isg = (i == 0) | (i == 63) | (i == LL - 64) | (i == LL - 1);
    int jlo, jhi, ne = 0;
    int extra[4];
    if (isg) { jlo = 0; jhi = LL - 1; }
    else {
        jlo = i - HALF_WIN; if (jlo < 0) jlo = 0;
        jhi = i + HALF_WIN; if (jhi > LL - 1) jhi = LL - 1;
        const int g[4] = {0, 63, LL - 64, LL - 1};
#pragma unroll
        for (int e = 0; e < 4; e++)
            if (g[e] < jlo || g[e] > jhi) extra[ne++] = g[e];
    }
    const int nband = jhi - jlo + 1;
    const int nj = nband + ne;

    if (t < HD) qs[t] = qw[(base + i) * HD + t];
    __syncthreads();

    const float scale = 0.17677669529663687f;  // 1/sqrt(32)

    // scores + local max
    float lmax = -1e30f;
    for (int idx = t; idx < nj; idx += 256) {
        int j = (idx < nband) ? (jlo + idx) : extra[idx - nband];
        const float4* kp = (const float4*)(kw + (base + j) * HD);
        float dot = 0.f;
#pragma unroll
        for (int d4 = 0; d4 < 8; d4++) {
            float4 kv = kp[d4];
            dot += qs[d4 * 4 + 0] * kv.x + qs[d4 * 4 + 1] * kv.y +
                   qs[d4 * 4 + 2] * kv.z + qs[d4 * 4 + 3] * kv.w;
        }
        float s = dot * scale;
        sc[j] = s;
        lmax = fmaxf(lmax, s);
    }
    red[t] = lmax; __syncthreads();
    for (int s = 128; s > 0; s >>= 1) {
        if (t < s) red[t] = fmaxf(red[t], red[t + s]);
        __syncthreads();
    }
    const float m = red[0];
    __syncthreads();

    // exp + local sum
    float lsum = 0.f;
    for (int idx = t; idx < nj; idx += 256) {
        int j = (idx < nband) ? (jlo + idx) : extra[idx - nband];
        float p = __expf(sc[j] - m);
        sc[j] = p;
        lsum += p;
    }
    red[t] = lsum; __syncthreads();
    for (int s = 128; s > 0; s >>= 1) {
        if (t < s) red[t] += red[t + s];
        __syncthreads();
    }
    const float denom = red[0];
    __syncthreads();

    // PV: 8 j-chunks x 32 d-lanes
    const int d = t & 31, g8 = t >> 5;
    float acc = 0.f;
    for (int idx = g8; idx < nj; idx += 8) {
        int j = (idx < nband) ? (jlo + idx) : extra[idx - nband];
        acc += sc[j] * vw[(base + j) * HD + d];
    }
    red[g8 * 32 + d] = acc;
    __syncthreads();
    if (t < 32) {
        float s = 0.f;
#pragma unroll
        for (int g = 0; g < 8; g++) s += red[g * 32 + t];
        s /= denom;
        int b = bh / HEADS, h = bh % HEADS;
        // output channel index ci = d*8 + h
        obuf[((size_t)b * LL + i) * CC + t * 8 + h] = s;
    }
}

// ---------------- Kernel 3: output projection --------------------------------
// out[b,co,l] = sum_ci obuf[b,l,ci] * w2[ci,co] + b2[co]
__global__ __launch_bounds__(256) void proj_kernel(const float* __restrict__ obuf,
                                                   const float* __restrict__ w2,
                                                   const float* __restrict__ b2,
                                                   float* __restrict__ out) {
    __shared__ float As[64][65];
    __shared__ float Bs[64][65];
    const int co0 = blockIdx.x * 64;
    const int l0  = blockIdx.y * 64;
    const int b   = blockIdx.z;
    const int t   = threadIdx.x;
    const int ll  = t & 63;
    const int cog = t >> 6;
    float acc[16];
#pragma unroll
    for (int k = 0; k < 16; k++) acc[k] = 0.f;

    for (int c0 = 0; c0 < CC; c0 += 64) {
#pragma unroll
        for (int k = 0; k < 16; k++) {
            int idx = k * 256 + t;
            int r = idx >> 6, cc = idx & 63;
            As[r][cc] = obuf[((size_t)b * LL + l0 + r) * CC + c0 + cc];
            Bs[r][cc] = w2[(size_t)(c0 + r) * CC + co0 + cc];
        }
        __syncthreads();
#pragma unroll
        for (int ci = 0; ci < 64; ci++) {
            float a = As[ll][ci];
#pragma unroll
            for (int k = 0; k < 16; k++) acc[k] += a * Bs[ci][cog * 16 + k];
        }
        __syncthreads();
    }

#pragma unroll
    for (int k = 0; k < 16; k++) {
        int co = co0 + cog * 16 + k;
        float val = acc[k] + b2[co];
        out[((size_t)b * CC + co) * LL + l0 + ll] = val;
    }
}

extern "C" void kernel_launch(void* const* d_in, const int* in_sizes, int n_in,
                              void* d_out, int out_size, void* d_ws, size_t ws_size,
                              hipStream_t stream) {
    const float* x  = (const float*)d_in[0];
    const float* w1 = (const float*)d_in[1];
    const float* b1 = (const float*)d_in[2];
    const float* w2 = (const float*)d_in[3];
    const float* b2 = (const float*)d_in[4];
    float* out = (float*)d_out;

    const size_t QKV_ELEMS = (size_t)BB * HEADS * LL * HD;  // 2,097,152
    float* qw = (float*)d_ws;
    float* kw = qw + QKV_ELEMS;
    float* vw = kw + QKV_ELEMS;
    float* ob = vw + QKV_ELEMS;

    qkv_kernel<<<dim3(12, 64, 2), 256, 0, stream>>>(x, w1, b1, qw, kw, vw);
    attn_kernel<<<dim3(LL, BB * HEADS), 256, 0, stream>>>(qw, kw, vw, ob);
    proj_kernel<<<dim3(4, 64, 2), 256, 0, stream>>>(ob, w2, b2, out);
}

// Round 3
// 312.629 us; speedup vs baseline: 6.6255x; 6.6255x over previous
//
#include <hip/hip_runtime.h>
#include <hip/hip_bf16.h>

#define BB 2
#define CC 256
#define HEADS 8
#define HD 32
#define LL 4096
#define HALF_WIN 512

using short8  = __attribute__((ext_vector_type(8))) short;
using float4v = __attribute__((ext_vector_type(4))) float;

__device__ __forceinline__ ushort f2bf(float x) {
    uint u = __float_as_uint(x);
    u += 0x7fff + ((u >> 16) & 1);
    return (ushort)(u >> 16);
}

// ---------------- Kernel 1: QKV projection -----------------------------------
// qkv[b,l,j] = sum_c x[b,c,l]*w1[c,j] + b1[j];  j = d*24 + h*3 + t3
// -> q_bf[bh][l][d], k_bf[bh][l][d], v_t[bh][d][l]   (bf16)
__global__ __launch_bounds__(256) void qkv_kernel(const float* __restrict__ x,
                                                  const float* __restrict__ w1,
                                                  const float* __restrict__ b1,
                                                  ushort* __restrict__ qb,
                                                  ushort* __restrict__ kb,
                                                  ushort* __restrict__ vt) {
    __shared__ __align__(16) float As[64][68];  // [c][l]
    __shared__ __align__(16) float Bs[64][68];  // [c][j]
    const int j0 = blockIdx.x * 64;
    const int l0 = blockIdx.y * 64;
    const int b  = blockIdx.z;
    const int t  = threadIdx.x;
    const int tx = t & 15;   // l group
    const int ty = t >> 4;   // j group
    float acc[4][4] = {};

    for (int c0 = 0; c0 < CC; c0 += 64) {
#pragma unroll
        for (int k = 0; k < 16; k++) {
            int idx = k * 256 + t;
            int al = idx & 63, ac = idx >> 6;
            As[ac][al] = x[((size_t)b * CC + c0 + ac) * LL + l0 + al];
            int br = idx >> 6, bc = idx & 63;
            Bs[br][bc] = w1[(size_t)(c0 + br) * 768 + j0 + bc];
        }
        __syncthreads();
#pragma unroll
        for (int ci = 0; ci < 64; ci++) {
            float4 av = *(const float4*)&As[ci][tx * 4];
            float4 bv = *(const float4*)&Bs[ci][ty * 4];
            float aa[4] = {av.x, av.y, av.z, av.w};
            float bb[4] = {bv.x, bv.y, bv.z, bv.w};
#pragma unroll
            for (int a = 0; a < 4; a++)
#pragma unroll
                for (int e = 0; e < 4; e++) acc[a][e] += aa[a] * bb[e];
        }
        __syncthreads();
    }

#pragma unroll
    for (int a = 0; a < 4; a++) {
        int l = l0 + tx * 4 + a;
#pragma unroll
        for (int e = 0; e < 4; e++) {
            int j = j0 + ty * 4 + e;
            float val = acc[a][e] + b1[j];
            int t3 = j % 3, h = (j / 3) & 7, d = j / 24;
            ushort bfv = f2bf(val);
            size_t bh = (size_t)(b * 8 + h);
            if (t3 == 0)      qb[(bh * LL + l) * HD + d] = bfv;
            else if (t3 == 1) kb[(bh * LL + l) * HD + d] = bfv;
            else              vt[(bh * HD + d) * LL + l] = bfv;
        }
    }
}

// ---------------- Kernel 2: banded MFMA attention ----------------------------
// Block = (i-tile of 64 rows, bh). 4 waves x 16 rows. No __syncthreads.
// S^T = mfma(Kfrag, Qfrag); exp (no max-sub: scores bounded); P->LDS->A-frag;
// PV pairs of j-tiles (K=32). Denominator streamed per-lane.
__global__ __launch_bounds__(256) void attn_kernel(const ushort* __restrict__ qb,
                                                   const ushort* __restrict__ kb,
                                                   const ushort* __restrict__ vt,
                                                   float* __restrict__ obuf) {
    __shared__ __align__(16) ushort pshare[4][640];  // per-wave 16 rows x 80 B
    const int bx = blockIdx.x;
    const int it = (bx == 0) ? 0 : (bx == 1) ? 63 : bx - 1;  // full tiles first
    const int bh = blockIdx.y;
    const int i0 = it * 64;
    const int t  = threadIdx.x;
    const int w  = t >> 6;
    const int ln = t & 63;
    const int c  = ln & 15;   // col lane (i-local for S^T, row for A-frag)
    const int g  = ln >> 4;   // lane group 0..3

    const size_t base = (size_t)bh * LL * HD;
    const int i = i0 + w * 16 + c;
    const bool iglob = (i == 0) | (i == 63) | (i == LL - 64) | (i == LL - 1);

    // Q fragment (B operand of S^T): lane holds Q[i][g*8 .. g*8+7]
    const short8 qf = *(const short8*)(qb + base + (size_t)i * HD + g * 8);

    float4v o0 = {0.f, 0.f, 0.f, 0.f}, o1 = {0.f, 0.f, 0.f, 0.f};
    float dsum = 0.f;

    int t0, t1, ne = 0;
    int extra[4];
    const bool full = (it == 0) | (it == 63);
    if (full) { t0 = 0; t1 = 255; }
    else {
        t0 = it * 4 - 32; if (t0 < 0) t0 = 0;
        t1 = it * 4 + 35; if (t1 > 255) t1 = 255;
        const int gt[4] = {0, 3, 252, 255};
#pragma unroll
        for (int e = 0; e < 4; e++)
            if (gt[e] < t0 || gt[e] > t1) extra[ne++] = gt[e];
    }
    const int nbt = t1 - t0 + 1;
    const int nt = nbt + ne;
    const int npair = (nt + 1) >> 1;

    ushort* wb = &pshare[w][0];
    const float scale = 0.17677669529663687f;  // 1/sqrt(32)
    const ushort* vb = vt + (size_t)bh * HD * LL;

    for (int m = 0; m < npair; m++) {
        const int n0 = 2 * m, n1 = 2 * m + 1;
        const int tA = (n0 < nbt) ? t0 + n0 : extra[n0 - nbt];
        const bool vBv = (n1 < nt);
        const int tB = (n1 < nbt) ? t0 + n1 : (vBv ? extra[n1 - nbt] : t0);

        // K fragments (A operand): lane holds K[tile*16 + c][g*8 ..]
        const short8 kfA = *(const short8*)(kb + base + (size_t)(tA * 16 + c) * HD + g * 8);
        const short8 kfB = *(const short8*)(kb + base + (size_t)(tB * 16 + c) * HD + g * 8);
        float4v zero = {0.f, 0.f, 0.f, 0.f};
        float4v sA = __builtin_amdgcn_mfma_f32_16x16x32_bf16(kfA, qf, zero, 0, 0, 0);
        float4v sB = __builtin_amdgcn_mfma_f32_16x16x32_bf16(kfB, qf, zero, 0, 0, 0);

        // mask + exp; S^T: lane holds rows j = tile*16 + g*4 + r, col i
        float pA[4], pB[4];
#pragma unroll
        for (int r = 0; r < 4; r++) {
            int j = tA * 16 + g * 4 + r;
            bool band = (unsigned)(i - j + HALF_WIN) <= 2u * HALF_WIN;
            bool jg = (j == 0) | (j == 63) | (j == LL - 64) | (j == LL - 1);
            pA[r] = (band | jg | iglob) ? __expf(sA[r] * scale) : 0.f;
            dsum += pA[r];
        }
#pragma unroll
        for (int r = 0; r < 4; r++) {
            int j = tB * 16 + g * 4 + r;
            bool band = (unsigned)(i - j + HALF_WIN) <= 2u * HALF_WIN;
            bool jg = (j == 0) | (j == 63) | (j == LL - 64) | (j == LL - 1);
            pB[r] = (vBv & (band | jg | iglob)) ? __expf(sB[r] * scale) : 0.f;
            dsum += pB[r];
        }

        // pack to bf16 and stage P^T -> A-layout via per-wave LDS (no barrier:
        // same-wave DS ops are in-order)
        uint2 ua, ub;
        ua.x = (uint)f2bf(pA[0]) | ((uint)f2bf(pA[1]) << 16);
        ua.y = (uint)f2bf(pA[2]) | ((uint)f2bf(pA[3]) << 16);
        ub.x = (uint)f2bf(pB[0]) | ((uint)f2bf(pB[1]) << 16);
        ub.y = (uint)f2bf(pB[2]) | ((uint)f2bf(pB[3]) << 16);
        *(uint2*)&wb[c * 40 + 4 * g]      = ua;  // even tile: j-local 4g..4g+3
        *(uint2*)&wb[c * 40 + 16 + 4 * g] = ub;  // odd tile:  j-local 16+4g..

        // A-frag: lane holds P[i-local = c][k = g*8 .. g*8+7]
        const short8 pf = *(const short8*)&wb[c * 40 + 8 * g];

        // V B-frags: lane holds V[j = jv .. jv+7][d = (half)*16 + c]
        const int jv = (g < 2) ? tA * 16 + g * 8 : tB * 16 + (g - 2) * 8;
        const short8 v0f = *(const short8*)(vb + (size_t)c * LL + jv);
        const short8 v1f = *(const short8*)(vb + (size_t)(16 + c) * LL + jv);
        o0 = __builtin_amdgcn_mfma_f32_16x16x32_bf16(pf, v0f, o0, 0, 0, 0);
        o1 = __builtin_amdgcn_mfma_f32_16x16x32_bf16(pf, v1f, o1, 0, 0, 0);
    }

    // denominator: lane owns col i; sum the 4 lane-groups
    dsum += __shfl_xor(dsum, 16);
    dsum += __shfl_xor(dsum, 32);

    const int b = bh >> 3, hh = bh & 7;
#pragma unroll
    for (int r = 0; r < 4; r++) {
        float dn = __shfl(dsum, g * 4 + r);   // lane (g*4+r) holds i-local g*4+r
        float inv = 1.0f / dn;
        int irow = i0 + w * 16 + g * 4 + r;
        size_t rowb = ((size_t)b * LL + irow) * CC;
        obuf[rowb + (size_t)c * 8 + hh]        = o0[r] * inv;  // ci = d*8 + h
        obuf[rowb + (size_t)(16 + c) * 8 + hh] = o1[r] * inv;
    }
}

// ---------------- Kernel 3: output projection --------------------------------
// out[b,co,l] = sum_ci obuf[b,l,ci] * w2[ci,co] + b2[co]
__global__ __launch_bounds__(256) void proj_kernel(const float* __restrict__ obuf,
                                                   const float* __restrict__ w2,
                                                   const float* __restrict__ b2,
                                                   float* __restrict__ out) {
    __shared__ __align__(16) float As[64][68];  // [ci][l]
    __shared__ __align__(16) float Bs[64][68];  // [ci][co]
    const int co0 = blockIdx.x * 64;
    const int l0  = blockIdx.y * 64;
    const int b   = blockIdx.z;
    const int t   = threadIdx.x;
    const int tx  = t & 15;   // l group
    const int ty  = t >> 4;   // co group
    float acc[4][4] = {};

    for (int c0 = 0; c0 < CC; c0 += 64) {
#pragma unroll
        for (int k = 0; k < 16; k++) {
            int idx = k * 256 + t;
            int cc = idx & 63, r = idx >> 6;
            As[cc][r] = obuf[((size_t)b * LL + l0 + r) * CC + c0 + cc];
            int br = idx >> 6, bc = idx & 63;
            Bs[br][bc] = w2[(size_t)(c0 + br) * CC + co0 + bc];
        }
        __syncthreads();
#pragma unroll
        for (int ci = 0; ci < 64; ci++) {
            float4 av = *(const float4*)&As[ci][tx * 4];
            float4 bv = *(const float4*)&Bs[ci][ty * 4];
            float aa[4] = {av.x, av.y, av.z, av.w};
            float bb[4] = {bv.x, bv.y, bv.z, bv.w};
#pragma unroll
            for (int a = 0; a < 4; a++)
#pragma unroll
                for (int e = 0; e < 4; e++) acc[a][e] += aa[a] * bb[e];
        }
        __syncthreads();
    }

#pragma unroll
    for (int a = 0; a < 4; a++) {
        int l = l0 + tx * 4 + a;
#pragma unroll
        for (int e = 0; e < 4; e++) {
            int co = co0 + ty * 4 + e;
            out[((size_t)b * CC + co) * LL + l] = acc[a][e] + b2[co];
        }
    }
}

extern "C" void kernel_launch(void* const* d_in, const int* in_sizes, int n_in,
                              void* d_out, int out_size, void* d_ws, size_t ws_size,
                              hipStream_t stream) {
    const float* x  = (const float*)d_in[0];
    const float* w1 = (const float*)d_in[1];
    const float* b1 = (const float*)d_in[2];
    const float* w2 = (const float*)d_in[3];
    const float* b2 = (const float*)d_in[4];
    float* out = (float*)d_out;

    const size_t QKE = (size_t)BB * HEADS * LL * HD;  // 2,097,152 elems
    ushort* qb = (ushort*)d_ws;
    ushort* kb = qb + QKE;
    ushort* vt = kb + QKE;
    float*  ob = (float*)(vt + QKE);

    qkv_kernel<<<dim3(12, 64, 2), 256, 0, stream>>>(x, w1, b1, qb, kb, vt);
    attn_kernel<<<dim3(64, 16), 256, 0, stream>>>(qb, kb, vt, ob);
    proj_kernel<<<dim3(4, 64, 2), 256, 0, stream>>>(ob, w2, b2, out);
}

// Round 4
// 260.132 us; speedup vs baseline: 7.9626x; 1.2018x over previous
//
#include <hip/hip_runtime.h>
#include <hip/hip_bf16.h>

#define BB 2
#define CC 256
#define HEADS 8
#define HD 32
#define LL 4096
#define HALF_WIN 512

using short8  = __attribute__((ext_vector_type(8))) short;
using float4v = __attribute__((ext_vector_type(4))) float;

__device__ __forceinline__ ushort f2bf(float x) {
    uint u = __float_as_uint(x);
    u += 0x7fff + ((u >> 16) & 1);
    return (ushort)(u >> 16);
}
__device__ __forceinline__ float ubf(ushort u) {
    return __uint_as_float((uint)u << 16);
}

// ---------------- Kernel 1: QKV projection (fp32 VALU) -----------------------
// qkv[b,l,j] = sum_c x[b,c,l]*w1[c,j] + b1[j];  j = d*24 + h*3 + t3
// q/k stored as slab layout [bh][d>>3][l][8] (bf16); v as [bh][d][l] (bf16)
__global__ __launch_bounds__(256) void qkv_kernel(const float* __restrict__ x,
                                                  const float* __restrict__ w1,
                                                  const float* __restrict__ b1,
                                                  ushort* __restrict__ qb,
                                                  ushort* __restrict__ kb,
                                                  ushort* __restrict__ vt) {
    __shared__ __align__(16) float As[64][68];  // [c][l]
    __shared__ __align__(16) float Bs[64][68];  // [c][j]
    const int j0 = blockIdx.x * 64;
    const int l0 = blockIdx.y * 64;
    const int b  = blockIdx.z;
    const int t  = threadIdx.x;
    const int tx = t & 15;   // l group
    const int ty = t >> 4;   // j group
    float acc[4][4] = {};

    for (int c0 = 0; c0 < CC; c0 += 64) {
#pragma unroll
        for (int k = 0; k < 16; k++) {
            int idx = k * 256 + t;
            int al = idx & 63, ac = idx >> 6;
            As[ac][al] = x[((size_t)b * CC + c0 + ac) * LL + l0 + al];
            int br = idx >> 6, bc = idx & 63;
            Bs[br][bc] = w1[(size_t)(c0 + br) * 768 + j0 + bc];
        }
        __syncthreads();
#pragma unroll
        for (int ci = 0; ci < 64; ci++) {
            float4 av = *(const float4*)&As[ci][tx * 4];
            float4 bv = *(const float4*)&Bs[ci][ty * 4];
            float aa[4] = {av.x, av.y, av.z, av.w};
            float bb[4] = {bv.x, bv.y, bv.z, bv.w};
#pragma unroll
            for (int a = 0; a < 4; a++)
#pragma unroll
                for (int e = 0; e < 4; e++) acc[a][e] += aa[a] * bb[e];
        }
        __syncthreads();
    }

#pragma unroll
    for (int a = 0; a < 4; a++) {
        int l = l0 + tx * 4 + a;
#pragma unroll
        for (int e = 0; e < 4; e++) {
            int j = j0 + ty * 4 + e;
            float val = acc[a][e] + b1[j];
            int t3 = j % 3, h = (j / 3) & 7, d = j / 24;
            ushort bfv = f2bf(val);
            size_t bh = (size_t)(b * 8 + h);
            if (t3 == 0)      qb[((bh * 4 + (d >> 3)) * LL + l) * 8 + (d & 7)] = bfv;
            else if (t3 == 1) kb[((bh * 4 + (d >> 3)) * LL + l) * 8 + (d & 7)] = bfv;
            else              vt[(bh * HD + d) * LL + l] = bfv;
        }
    }
}

// ---------------- Kernel 2: banded MFMA attention (band-only) ----------------
// Block = (i-tile of 64 rows, bh). 4 waves x 16 rows. No __syncthreads.
// All tiles do band + global-j-columns only (<=36 MFMA pair-iters). The 4
// global ROWS per bh are overwritten afterwards by attn_global_kernel.
__global__ __launch_bounds__(256) void attn_kernel(const ushort* __restrict__ qb,
                                                   const ushort* __restrict__ kb,
                                                   const ushort* __restrict__ vt,
                                                   ushort* __restrict__ obuf) {
    __shared__ __align__(16) ushort pshare[4][640];  // per-wave 16 rows x 80 B
    const int it = blockIdx.x;
    const int bh = blockIdx.y;
    const int i0 = it * 64;
    const int t  = threadIdx.x;
    const int w  = t >> 6;
    const int ln = t & 63;
    const int c  = ln & 15;   // col lane (i-local for S^T, row for A-frag)
    const int g  = ln >> 4;   // lane group 0..3 (slab index)

    const size_t slab = ((size_t)bh * 4 + g) * LL;
    const int i = i0 + w * 16 + c;
    const bool iglob = (i == 0) | (i == 63) | (i == LL - 64) | (i == LL - 1);

    // Q fragment (B operand of S^T): lane holds Q[i][g*8 .. g*8+7]
    const short8 qf = *(const short8*)(qb + (slab + i) * 8);

    float4v o0 = {0.f, 0.f, 0.f, 0.f}, o1 = {0.f, 0.f, 0.f, 0.f};
    float dsum = 0.f;

    int t0, t1, ne = 0;
    int extra[4];
    t0 = it * 4 - 32; if (t0 < 0) t0 = 0;
    t1 = it * 4 + 35; if (t1 > 255) t1 = 255;
    const int gt[4] = {0, 3, 252, 255};
#pragma unroll
    for (int e = 0; e < 4; e++)
        if (gt[e] < t0 || gt[e] > t1) extra[ne++] = gt[e];
    const int nbt = t1 - t0 + 1;
    const int nt = nbt + ne;
    const int npair = (nt + 1) >> 1;

    ushort* wb = &pshare[w][0];
    const float scale = 0.17677669529663687f;  // 1/sqrt(32)
    const ushort* vb = vt + (size_t)bh * HD * LL;

    for (int m = 0; m < npair; m++) {
        const int n0 = 2 * m, n1 = 2 * m + 1;
        const int tA = (n0 < nbt) ? t0 + n0 : extra[n0 - nbt];
        const bool vBv = (n1 < nt);
        const int tB = (n1 < nbt) ? t0 + n1 : (vBv ? extra[n1 - nbt] : t0);

        // K fragments (A operand): lane holds K[tile*16 + c][g*8 ..]
        const short8 kfA = *(const short8*)(kb + (slab + tA * 16 + c) * 8);
        const short8 kfB = *(const short8*)(kb + (slab + tB * 16 + c) * 8);
        float4v zero = {0.f, 0.f, 0.f, 0.f};
        float4v sA = __builtin_amdgcn_mfma_f32_16x16x32_bf16(kfA, qf, zero, 0, 0, 0);
        float4v sB = __builtin_amdgcn_mfma_f32_16x16x32_bf16(kfB, qf, zero, 0, 0, 0);

        // mask + exp; S^T: lane holds rows j = tile*16 + g*4 + r, col i
        float pA[4], pB[4];
#pragma unroll
        for (int r = 0; r < 4; r++) {
            int j = tA * 16 + g * 4 + r;
            bool band = (unsigned)(i - j + HALF_WIN) <= 2u * HALF_WIN;
            bool jg = (j == 0) | (j == 63) | (j == LL - 64) | (j == LL - 1);
            pA[r] = (band | jg | iglob) ? __expf(sA[r] * scale) : 0.f;
            dsum += pA[r];
        }
#pragma unroll
        for (int r = 0; r < 4; r++) {
            int j = tB * 16 + g * 4 + r;
            bool band = (unsigned)(i - j + HALF_WIN) <= 2u * HALF_WIN;
            bool jg = (j == 0) | (j == 63) | (j == LL - 64) | (j == LL - 1);
            pB[r] = (vBv & (band | jg | iglob)) ? __expf(sB[r] * scale) : 0.f;
            dsum += pB[r];
        }

        // pack to bf16, stage P^T -> A-layout via per-wave LDS (same-wave DS
        // ordering, no barrier needed)
        uint2 ua, ub2;
        ua.x  = (uint)f2bf(pA[0]) | ((uint)f2bf(pA[1]) << 16);
        ua.y  = (uint)f2bf(pA[2]) | ((uint)f2bf(pA[3]) << 16);
        ub2.x = (uint)f2bf(pB[0]) | ((uint)f2bf(pB[1]) << 16);
        ub2.y = (uint)f2bf(pB[2]) | ((uint)f2bf(pB[3]) << 16);
        *(uint2*)&wb[c * 40 + 4 * g]      = ua;
        *(uint2*)&wb[c * 40 + 16 + 4 * g] = ub2;

        // A-frag: lane holds P[i-local = c][k = g*8 .. g*8+7]
        const short8 pf = *(const short8*)&wb[c * 40 + 8 * g];

        // V B-frags: lane holds V[j = jv .. jv+7][d = (half)*16 + c]
        const int jv = (g < 2) ? tA * 16 + g * 8 : tB * 16 + (g - 2) * 8;
        const short8 v0f = *(const short8*)(vb + (size_t)c * LL + jv);
        const short8 v1f = *(const short8*)(vb + (size_t)(16 + c) * LL + jv);
        o0 = __builtin_amdgcn_mfma_f32_16x16x32_bf16(pf, v0f, o0, 0, 0, 0);
        o1 = __builtin_amdgcn_mfma_f32_16x16x32_bf16(pf, v1f, o1, 0, 0, 0);
    }

    // denominator: lane owns col i; sum the 4 lane-groups
    dsum += __shfl_xor(dsum, 16);
    dsum += __shfl_xor(dsum, 32);

    const int b = bh >> 3, hh = bh & 7;
#pragma unroll
    for (int r = 0; r < 4; r++) {
        float dn = __shfl(dsum, g * 4 + r);
        float inv = 1.0f / dn;
        int irow = i0 + w * 16 + g * 4 + r;
        size_t rowb = ((size_t)b * LL + irow) * CC;
        obuf[rowb + (size_t)c * 8 + hh]        = f2bf(o0[r] * inv);  // ci = d*8+h
        obuf[rowb + (size_t)(16 + c) * 8 + hh] = f2bf(o1[r] * inv);
    }
}

// ---------------- Kernel 2b: global rows (4 per bh, full softmax) ------------
__global__ __launch_bounds__(256) void attn_global_kernel(const ushort* __restrict__ qb,
                                                          const ushort* __restrict__ kb,
                                                          const ushort* __restrict__ vt,
                                                          ushort* __restrict__ obuf) {
    __shared__ float sc[LL];
    __shared__ float red[256];
    __shared__ float qs[HD];
    const int gsel = blockIdx.x & 3;
    const int bh   = blockIdx.x >> 2;
    const int gidx[4] = {0, 63, LL - 64, LL - 1};
    const int i = gidx[gsel];
    const int t = threadIdx.x;
    const float scale = 0.17677669529663687f;

    if (t < HD) qs[t] = ubf(qb[(((size_t)bh * 4 + (t >> 3)) * LL + i) * 8 + (t & 7)]);
    __syncthreads();

    float lsum = 0.f;
    for (int j = t; j < LL; j += 256) {
        float dot = 0.f;
#pragma unroll
        for (int s = 0; s < 4; s++) {
            const short8 kf = *(const short8*)(kb + (((size_t)bh * 4 + s) * LL + j) * 8);
#pragma unroll
            for (int e = 0; e < 8; e++) dot += qs[s * 8 + e] * ubf((ushort)kf[e]);
        }
        float p = __expf(dot * scale);
        sc[j] = p;
        lsum += p;
    }
    red[t] = lsum; __syncthreads();
    for (int s = 128; s > 0; s >>= 1) {
        if (t < s) red[t] += red[t + s];
        __syncthreads();
    }
    const float inv = 1.0f / red[0];
    __syncthreads();

    const int d = t & 31, jg = t >> 5;
    float acc = 0.f;
    const ushort* vrow = vt + ((size_t)bh * HD + d) * LL;
    for (int j = jg; j < LL; j += 8) acc += sc[j] * ubf(vrow[j]);
    red[t] = acc; __syncthreads();
    if (t < 32) {
        float s = 0.f;
#pragma unroll
        for (int gg = 0; gg < 8; gg++) s += red[gg * 32 + t];
        int b = bh >> 3, hh = bh & 7;
        obuf[((size_t)b * LL + i) * CC + t * 8 + hh] = f2bf(s * inv);
    }
}

// ---------------- Kernel 3: output projection (fp32 VALU) --------------------
// out[b,co,l] = sum_ci obuf[b,l,ci] * w2[ci,co] + b2[co]
__global__ __launch_bounds__(256) void proj_kernel(const ushort* __restrict__ obuf,
                                                   const float* __restrict__ w2,
                                                   const float* __restrict__ b2,
                                                   float* __restrict__ out) {
    __shared__ __align__(16) float As[64][68];  // [ci][l]
    __shared__ __align__(16) float Bs[64][68];  // [ci][co]
    const int co0 = blockIdx.x * 64;
    const int l0  = blockIdx.y * 64;
    const int b   = blockIdx.z;
    const int t   = threadIdx.x;
    const int tx  = t & 15;   // l group
    const int ty  = t >> 4;   // co group
    float acc[4][4] = {};

    for (int c0 = 0; c0 < CC; c0 += 64) {
#pragma unroll
        for (int k = 0; k < 16; k++) {
            int idx = k * 256 + t;
            int cc = idx & 63, r = idx >> 6;
            As[cc][r] = ubf(obuf[((size_t)b * LL + l0 + r) * CC + c0 + cc]);
            int br = idx >> 6, bc = idx & 63;
            Bs[br][bc] = w2[(size_t)(c0 + br) * CC + co0 + bc];
        }
        __syncthreads();
#pragma unroll
        for (int ci = 0; ci < 64; ci++) {
            float4 av = *(const float4*)&As[ci][tx * 4];
            float4 bv = *(const float4*)&Bs[ci][ty * 4];
            float aa[4] = {av.x, av.y, av.z, av.w};
            float bb[4] = {bv.x, bv.y, bv.z, bv.w};
#pragma unroll
            for (int a = 0; a < 4; a++)
#pragma unroll
                for (int e = 0; e < 4; e++) acc[a][e] += aa[a] * bb[e];
        }
        __syncthreads();
    }

#pragma unroll
    for (int a = 0; a < 4; a++) {
        int l = l0 + tx * 4 + a;
#pragma unroll
        for (int e = 0; e < 4; e++) {
            int co = co0 + ty * 4 + e;
            out[((size_t)b * CC + co) * LL + l] = acc[a][e] + b2[co];
        }
    }
}

extern "C" void kernel_launch(void* const* d_in, const int* in_sizes, int n_in,
                              void* d_out, int out_size, void* d_ws, size_t ws_size,
                              hipStream_t stream) {
    const float* x  = (const float*)d_in[0];
    const float* w1 = (const float*)d_in[1];
    const float* b1 = (const float*)d_in[2];
    const float* w2 = (const float*)d_in[3];
    const float* b2 = (const float*)d_in[4];
    float* out = (float*)d_out;

    const size_t QKE = (size_t)BB * HEADS * LL * HD;  // 2,097,152 elems
    ushort* qb = (ushort*)d_ws;
    ushort* kb = qb + QKE;
    ushort* vt = kb + QKE;
    ushort* ob = vt + QKE;   // bf16 obuf [b][l][256]

    qkv_kernel<<<dim3(12, 64, 2), 256, 0, stream>>>(x, w1, b1, qb, kb, vt);
    attn_kernel<<<dim3(64, 16), 256, 0, stream>>>(qb, kb, vt, ob);
    attn_global_kernel<<<dim3(64), 256, 0, stream>>>(qb, kb, vt, ob);
    proj_kernel<<<dim3(4, 64, 2), 256, 0, stream>>>(ob, w2, b2, out);
}

// Round 5
// 185.418 us; speedup vs baseline: 11.1711x; 1.4029x over previous
//
#include <hip/hip_runtime.h>
#include <hip/hip_bf16.h>

#define BB 2
#define CC 256
#define HEADS 8
#define HD 32
#define LL 4096
#define HALF_WIN 512

using short8  = __attribute__((ext_vector_type(8))) short;
using float4v = __attribute__((ext_vector_type(4))) float;

__device__ __forceinline__ ushort f2bf(float x) {
    uint u = __float_as_uint(x);
    u += 0x7fff + ((u >> 16) & 1);
    return (ushort)(u >> 16);
}
__device__ __forceinline__ float ubf(ushort u) {
    return __uint_as_float((uint)u << 16);
}

// ---------------- Kernel 1: QKV projection (fp32 VALU) -----------------------
// qkv[b,l,j] = sum_c x[b,c,l]*w1[c,j] + b1[j];  j = d*24 + h*3 + t3
// q/k stored as slab layout [bh][d>>3][l][8] (bf16); v as [bh][d][l] (bf16)
__global__ __launch_bounds__(256) void qkv_kernel(const float* __restrict__ x,
                                                  const float* __restrict__ w1,
                                                  const float* __restrict__ b1,
                                                  ushort* __restrict__ qb,
                                                  ushort* __restrict__ kb,
                                                  ushort* __restrict__ vt) {
    __shared__ __align__(16) float As[64][68];  // [c][l]
    __shared__ __align__(16) float Bs[64][68];  // [c][j]
    const int j0 = blockIdx.x * 64;
    const int l0 = blockIdx.y * 64;
    const int b  = blockIdx.z;
    const int t  = threadIdx.x;
    const int tx = t & 15;   // l group
    const int ty = t >> 4;   // j group
    float acc[4][4] = {};

    for (int c0 = 0; c0 < CC; c0 += 64) {
#pragma unroll
        for (int k = 0; k < 16; k++) {
            int idx = k * 256 + t;
            int al = idx & 63, ac = idx >> 6;
            As[ac][al] = x[((size_t)b * CC + c0 + ac) * LL + l0 + al];
            int br = idx >> 6, bc = idx & 63;
            Bs[br][bc] = w1[(size_t)(c0 + br) * 768 + j0 + bc];
        }
        __syncthreads();
#pragma unroll
        for (int ci = 0; ci < 64; ci++) {
            float4 av = *(const float4*)&As[ci][tx * 4];
            float4 bv = *(const float4*)&Bs[ci][ty * 4];
            float aa[4] = {av.x, av.y, av.z, av.w};
            float bb[4] = {bv.x, bv.y, bv.z, bv.w};
#pragma unroll
            for (int a = 0; a < 4; a++)
#pragma unroll
                for (int e = 0; e < 4; e++) acc[a][e] += aa[a] * bb[e];
        }
        __syncthreads();
    }

#pragma unroll
    for (int a = 0; a < 4; a++) {
        int l = l0 + tx * 4 + a;
#pragma unroll
        for (int e = 0; e < 4; e++) {
            int j = j0 + ty * 4 + e;
            float val = acc[a][e] + b1[j];
            int t3 = j % 3, h = (j / 3) & 7, d = j / 24;
            ushort bfv = f2bf(val);
            size_t bh = (size_t)(b * 8 + h);
            if (t3 == 0)      qb[((bh * 4 + (d >> 3)) * LL + l) * 8 + (d & 7)] = bfv;
            else if (t3 == 1) kb[((bh * 4 + (d >> 3)) * LL + l) * 8 + (d & 7)] = bfv;
            else              vt[(bh * HD + d) * LL + l] = bfv;
        }
    }
}

// ---------------- Kernel 2: banded MFMA attention (band-only) ----------------
// Block = (i-tile of 64 rows, bh). 4 waves x 16 rows. No __syncthreads.
// The 4 global ROWS per bh are overwritten later by the combine kernel.
__global__ __launch_bounds__(256) void attn_kernel(const ushort* __restrict__ qb,
                                                   const ushort* __restrict__ kb,
                                                   const ushort* __restrict__ vt,
                                                   ushort* __restrict__ obuf) {
    __shared__ __align__(16) ushort pshare[4][640];  // per-wave 16 rows x 80 B
    const int it = blockIdx.x;
    const int bh = blockIdx.y;
    const int i0 = it * 64;
    const int t  = threadIdx.x;
    const int w  = t >> 6;
    const int ln = t & 63;
    const int c  = ln & 15;   // col lane (i-local for S^T, row for A-frag)
    const int g  = ln >> 4;   // lane group 0..3 (slab index)

    const size_t slab = ((size_t)bh * 4 + g) * LL;
    const int i = i0 + w * 16 + c;
    const bool iglob = (i == 0) | (i == 63) | (i == LL - 64) | (i == LL - 1);

    // Q fragment (B operand of S^T): lane holds Q[i][g*8 .. g*8+7]
    const short8 qf = *(const short8*)(qb + (slab + i) * 8);

    float4v o0 = {0.f, 0.f, 0.f, 0.f}, o1 = {0.f, 0.f, 0.f, 0.f};
    float dsum = 0.f;

    int t0, t1, ne = 0;
    int extra[4];
    t0 = it * 4 - 32; if (t0 < 0) t0 = 0;
    t1 = it * 4 + 35; if (t1 > 255) t1 = 255;
    const int gt[4] = {0, 3, 252, 255};
#pragma unroll
    for (int e = 0; e < 4; e++)
        if (gt[e] < t0 || gt[e] > t1) extra[ne++] = gt[e];
    const int nbt = t1 - t0 + 1;
    const int nt = nbt + ne;
    const int npair = (nt + 1) >> 1;

    ushort* wb = &pshare[w][0];
    const float scale = 0.17677669529663687f;  // 1/sqrt(32)
    const ushort* vb = vt + (size_t)bh * HD * LL;

    for (int m = 0; m < npair; m++) {
        const int n0 = 2 * m, n1 = 2 * m + 1;
        const int tA = (n0 < nbt) ? t0 + n0 : extra[n0 - nbt];
        const bool vBv = (n1 < nt);
        const int tB = (n1 < nbt) ? t0 + n1 : (vBv ? extra[n1 - nbt] : t0);

        // K fragments (A operand): lane holds K[tile*16 + c][g*8 ..]
        const short8 kfA = *(const short8*)(kb + (slab + tA * 16 + c) * 8);
        const short8 kfB = *(const short8*)(kb + (slab + tB * 16 + c) * 8);
        float4v zero = {0.f, 0.f, 0.f, 0.f};
        float4v sA = __builtin_amdgcn_mfma_f32_16x16x32_bf16(kfA, qf, zero, 0, 0, 0);
        float4v sB = __builtin_amdgcn_mfma_f32_16x16x32_bf16(kfB, qf, zero, 0, 0, 0);

        // mask + exp; S^T: lane holds rows j = tile*16 + g*4 + r, col i
        float pA[4], pB[4];
#pragma unroll
        for (int r = 0; r < 4; r++) {
            int j = tA * 16 + g * 4 + r;
            bool band = (unsigned)(i - j + HALF_WIN) <= 2u * HALF_WIN;
            bool jg = (j == 0) | (j == 63) | (j == LL - 64) | (j == LL - 1);
            pA[r] = (band | jg | iglob) ? __expf(sA[r] * scale) : 0.f;
            dsum += pA[r];
        }
#pragma unroll
        for (int r = 0; r < 4; r++) {
            int j = tB * 16 + g * 4 + r;
            bool band = (unsigned)(i - j + HALF_WIN) <= 2u * HALF_WIN;
            bool jg = (j == 0) | (j == 63) | (j == LL - 64) | (j == LL - 1);
            pB[r] = (vBv & (band | jg | iglob)) ? __expf(sB[r] * scale) : 0.f;
            dsum += pB[r];
        }

        // pack to bf16, stage P^T -> A-layout via per-wave LDS (same-wave DS
        // ordering, no barrier needed)
        uint2 ua, ub2;
        ua.x  = (uint)f2bf(pA[0]) | ((uint)f2bf(pA[1]) << 16);
        ua.y  = (uint)f2bf(pA[2]) | ((uint)f2bf(pA[3]) << 16);
        ub2.x = (uint)f2bf(pB[0]) | ((uint)f2bf(pB[1]) << 16);
        ub2.y = (uint)f2bf(pB[2]) | ((uint)f2bf(pB[3]) << 16);
        *(uint2*)&wb[c * 40 + 4 * g]      = ua;
        *(uint2*)&wb[c * 40 + 16 + 4 * g] = ub2;

        // A-frag: lane holds P[i-local = c][k = g*8 .. g*8+7]
        const short8 pf = *(const short8*)&wb[c * 40 + 8 * g];

        // V B-frags: lane holds V[j = jv .. jv+7][d = (half)*16 + c]
        const int jv = (g < 2) ? tA * 16 + g * 8 : tB * 16 + (g - 2) * 8;
        const short8 v0f = *(const short8*)(vb + (size_t)c * LL + jv);
        const short8 v1f = *(const short8*)(vb + (size_t)(16 + c) * LL + jv);
        o0 = __builtin_amdgcn_mfma_f32_16x16x32_bf16(pf, v0f, o0, 0, 0, 0);
        o1 = __builtin_amdgcn_mfma_f32_16x16x32_bf16(pf, v1f, o1, 0, 0, 0);
    }

    // denominator: lane owns col i; sum the 4 lane-groups
    dsum += __shfl_xor(dsum, 16);
    dsum += __shfl_xor(dsum, 32);

    const int b = bh >> 3, hh = bh & 7;
#pragma unroll
    for (int r = 0; r < 4; r++) {
        float dn = __shfl(dsum, g * 4 + r);
        float inv = 1.0f / dn;
        int irow = i0 + w * 16 + g * 4 + r;
        size_t rowb = ((size_t)b * LL + irow) * CC;
        obuf[rowb + (size_t)c * 8 + hh]        = f2bf(o0[r] * inv);  // ci = d*8+h
        obuf[rowb + (size_t)(16 + c) * 8 + hh] = f2bf(o1[r] * inv);
    }
}

// ---------------- Kernel 2b: global rows, j-split partials -------------------
// grid (16 chunks, 16 bh); each block: 4 global rows x 256 j's -> partial
// sum-exp and partial PV into exclusive gpart[bh][ch][4][33] slot.
__global__ __launch_bounds__(256) void attn_global_partial(const ushort* __restrict__ qb,
                                                           const ushort* __restrict__ kb,
                                                           const ushort* __restrict__ vt,
                                                           float* __restrict__ gpart) {
    __shared__ float qs[4][32];
    __shared__ float sc[4][256];
    const int ch = blockIdx.x;
    const int bh = blockIdx.y;
    const int t  = threadIdx.x;
    const int gidx[4] = {0, 63, LL - 64, LL - 1};
    const float scale = 0.17677669529663687f;

    if (t < 128) {
        int r = t >> 5, dd = t & 31;
        int i = gidx[r];
        qs[r][dd] = ubf(qb[(((size_t)bh * 4 + (dd >> 3)) * LL + i) * 8 + (dd & 7)]);
    }
    __syncthreads();

    const int j = ch * 256 + t;
    float dot[4] = {};
#pragma unroll
    for (int s = 0; s < 4; s++) {
        const short8 kf = *(const short8*)(kb + (((size_t)bh * 4 + s) * LL + j) * 8);
#pragma unroll
        for (int e = 0; e < 8; e++) {
            float kv = ubf((ushort)kf[e]);
#pragma unroll
            for (int r = 0; r < 4; r++) dot[r] += qs[r][s * 8 + e] * kv;
        }
    }
#pragma unroll
    for (int r = 0; r < 4; r++) sc[r][t] = __expf(dot[r] * scale);
    __syncthreads();

    const int w = t >> 6, ln = t & 63;     // wave w owns global row w
    // partial denominator for row w
    float den = sc[w][ln] + sc[w][ln + 64] + sc[w][ln + 128] + sc[w][ln + 192];
#pragma unroll
    for (int o = 1; o < 64; o <<= 1) den += __shfl_xor(den, o);

    // partial PV for row w: 32 d-lanes x 2 j-halves
    const int dd = ln & 31, half = ln >> 5;
    float acc = 0.f;
    const ushort* vrow = vt + ((size_t)bh * HD + dd) * LL + ch * 256 + half * 128;
#pragma unroll
    for (int q8 = 0; q8 < 16; q8++) {
        const short8 v8 = *(const short8*)(vrow + q8 * 8);
#pragma unroll
        for (int e = 0; e < 8; e++) acc += sc[w][half * 128 + q8 * 8 + e] * ubf((ushort)v8[e]);
    }
    acc += __shfl_xor(acc, 32);

    float* gp = gpart + (((size_t)bh * 16 + ch) * 4 + w) * 33;
    if (ln < 32) gp[dd] = acc;
    if (ln == 0) gp[32] = den;
}

// ---------------- Kernel 2c: combine global-row partials ---------------------
__global__ __launch_bounds__(128) void attn_global_combine(const float* __restrict__ gpart,
                                                           ushort* __restrict__ obuf) {
    const int bh = blockIdx.x;
    const int t  = threadIdx.x;           // 0..127
    const int r  = t >> 5, dd = t & 31;
    const int gidx[4] = {0, 63, LL - 64, LL - 1};
    float pv = 0.f, den = 0.f;
#pragma unroll
    for (int ch = 0; ch < 16; ch++) {
        const float* gp = gpart + (((size_t)bh * 16 + ch) * 4 + r) * 33;
        pv  += gp[dd];
        den += gp[32];
    }
    const int b = bh >> 3, hh = bh & 7, i = gidx[r];
    obuf[((size_t)b * LL + i) * CC + dd * 8 + hh] = f2bf(pv / den);
}

// ---------------- Kernel 3a: w2 transpose + bf16 (once) ----------------------
__global__ __launch_bounds__(256) void w2t_kernel(const float* __restrict__ w2,
                                                  ushort* __restrict__ w2t) {
    __shared__ float tl[16][17];
    const int ci0 = blockIdx.x * 16, co0 = blockIdx.y * 16;
    const int tx = threadIdx.x & 15, ty = threadIdx.x >> 4;
    tl[ty][tx] = w2[(size_t)(ci0 + ty) * CC + co0 + tx];
    __syncthreads();
    w2t[(size_t)(co0 + ty) * CC + ci0 + tx] = f2bf(tl[tx][ty]);
}

// ---------------- Kernel 3: output projection (MFMA, zero-LDS) ---------------
// D[co][l] = sum_ci w2t[co][ci] * obuf[l][ci];  A = w2t, B = obuf (both [n/m][k]
// row-major -> 16B contiguous per-lane fragments straight from global).
__global__ __launch_bounds__(256) void proj_kernel(const ushort* __restrict__ obuf,
                                                   const ushort* __restrict__ w2t,
                                                   const float* __restrict__ b2,
                                                   float* __restrict__ out) {
    const int co0 = blockIdx.x * 16;
    const int l0  = blockIdx.y * 256 + (threadIdx.x >> 6) * 64;
    const int b   = blockIdx.z;
    const int ln  = threadIdx.x & 63;
    const int c   = ln & 15, g = ln >> 4;

    float4v acc[4] = {};
    const ushort* arow = w2t + (size_t)(co0 + c) * CC + g * 8;
    const ushort* brow = obuf + ((size_t)b * LL + l0 + c) * CC + g * 8;
#pragma unroll
    for (int ks = 0; ks < 8; ks++) {
        const short8 af = *(const short8*)(arow + ks * 32);
#pragma unroll
        for (int nf = 0; nf < 4; nf++) {
            const short8 bf = *(const short8*)(brow + (size_t)nf * 16 * CC + ks * 32);
            acc[nf] = __builtin_amdgcn_mfma_f32_16x16x32_bf16(af, bf, acc[nf], 0, 0, 0);
        }
    }
#pragma unroll
    for (int nf = 0; nf < 4; nf++) {
#pragma unroll
        for (int r = 0; r < 4; r++) {
            int co = co0 + g * 4 + r;
            int l  = l0 + nf * 16 + c;
            out[((size_t)b * CC + co) * LL + l] = acc[nf][r] + b2[co];
        }
    }
}

extern "C" void kernel_launch(void* const* d_in, const int* in_sizes, int n_in,
                              void* d_out, int out_size, void* d_ws, size_t ws_size,
                              hipStream_t stream) {
    const float* x  = (const float*)d_in[0];
    const float* w1 = (const float*)d_in[1];
    const float* b1 = (const float*)d_in[2];
    const float* w2 = (const float*)d_in[3];
    const float* b2 = (const float*)d_in[4];
    float* out = (float*)d_out;

    const size_t QKE = (size_t)BB * HEADS * LL * HD;  // 2,097,152 elems
    const size_t OBE = (size_t)BB * LL * CC;          // 2,097,152 elems
    ushort* qb  = (ushort*)d_ws;
    ushort* kb  = qb + QKE;
    ushort* vt  = kb + QKE;
    ushort* ob  = vt + QKE;                // bf16 obuf [b][l][256]
    float*  gp  = (float*)(ob + OBE);      // [16][16][4][33]
    ushort* w2t = (ushort*)(gp + 16 * 16 * 4 * 33);

    qkv_kernel<<<dim3(12, 64, 2), 256, 0, stream>>>(x, w1, b1, qb, kb, vt);
    w2t_kernel<<<dim3(16, 16), 256, 0, stream>>>(w2, w2t);
    attn_kernel<<<dim3(64, 16), 256, 0, stream>>>(qb, kb, vt, ob);
    attn_global_partial<<<dim3(16, 16), 256, 0, stream>>>(qb, kb, vt, gp);
    attn_global_combine<<<dim3(16), 128, 0, stream>>>(gp, ob);
    proj_kernel<<<dim3(16, 16, 2), 256, 0, stream>>>(ob, w2t, b2, out);
}

// Round 6
// 148.511 us; speedup vs baseline: 13.9472x; 1.2485x over previous
//
#include <hip/hip_runtime.h>
#include <hip/hip_bf16.h>

#define BB 2
#define CC 256
#define HEADS 8
#define HD 32
#define LL 4096
#define HALF_WIN 512

using short8  = __attribute__((ext_vector_type(8))) short;
using float4v = __attribute__((ext_vector_type(4))) float;

__device__ __forceinline__ ushort f2bf(float x) {
    uint u = __float_as_uint(x);
    u += 0x7fff + ((u >> 16) & 1);
    return (ushort)(u >> 16);
}
__device__ __forceinline__ float ubf(ushort u) {
    return __uint_as_float((uint)u << 16);
}

// ---------------- Kernel 0: weight transpose + bf16 (w1 and w2) --------------
__global__ __launch_bounds__(256) void wt_kernel(const float* __restrict__ w1,
                                                 const float* __restrict__ w2,
                                                 ushort* __restrict__ w1t,
                                                 ushort* __restrict__ w2t) {
    __shared__ float tl[16][17];
    const int tx = threadIdx.x & 15, ty = threadIdx.x >> 4;
    const int ci0 = blockIdx.x * 16;
    const int y = blockIdx.y;
    if (y < 48) {
        int j0 = y * 16;
        tl[ty][tx] = w1[(size_t)(ci0 + ty) * 768 + j0 + tx];
        __syncthreads();
        w1t[(size_t)(j0 + ty) * CC + ci0 + tx] = f2bf(tl[tx][ty]);
    } else {
        int co0 = (y - 48) * 16;
        tl[ty][tx] = w2[(size_t)(ci0 + ty) * CC + co0 + tx];
        __syncthreads();
        w2t[(size_t)(co0 + ty) * CC + ci0 + tx] = f2bf(tl[tx][ty]);
    }
}

// ---------------- Kernel 1: QKV projection (MFMA) ----------------------------
// D[j][l] = sum_c w1t[j][c] * xT[l][c] (+b1).  Block: 192 j x 64 l, K=256 fully
// staged in LDS (xT tile), zero K-loop barriers.  j-chunk of 192 spans one full
// 8-d slab (dg = blockIdx.x) for all 8 heads -> coalesced epilogue via LDS.
__global__ __launch_bounds__(256) void qkv_kernel(const float* __restrict__ x,
                                                  const ushort* __restrict__ w1t,
                                                  const float* __restrict__ b1,
                                                  ushort* __restrict__ qb,
                                                  ushort* __restrict__ kb,
                                                  ushort* __restrict__ vt) {
    __shared__ __align__(16) ushort xs[64 * 264];  // [l][c] pad->264; reused in epilogue
    const int dg = blockIdx.x;        // j-chunk dg*192; also the q/k d-slab index
    const int l0 = blockIdx.y * 64;
    const int b  = blockIdx.z;
    const int t  = threadIdx.x;
    const int w  = t >> 6, ln = t & 63, c = ln & 15, g = ln >> 4;

    // stage x^T tile: xs[l][cc] = bf16(x[b][cc][l0+l]); coalesced over l
    {
        const int l  = t & 63;
        const int cg = (t >> 6) * 4;
#pragma unroll
        for (int p = 0; p < 16; p++) {
            int c0 = p * 16 + cg;
            ushort4 v4;
            v4.x = f2bf(x[((size_t)b * CC + c0 + 0) * LL + l0 + l]);
            v4.y = f2bf(x[((size_t)b * CC + c0 + 1) * LL + l0 + l]);
            v4.z = f2bf(x[((size_t)b * CC + c0 + 2) * LL + l0 + l]);
            v4.w = f2bf(x[((size_t)b * CC + c0 + 3) * LL + l0 + l]);
            *(ushort4*)&xs[l * 264 + c0] = v4;
        }
    }
    __syncthreads();

    const int jbase = dg * 192 + w * 48;
    float4v acc[3][4] = {};
#pragma unroll
    for (int ks = 0; ks < 8; ks++) {
        short8 af[3], bfr[4];
#pragma unroll
        for (int jt = 0; jt < 3; jt++)
            af[jt] = *(const short8*)(w1t + (size_t)(jbase + jt * 16 + c) * CC + ks * 32 + g * 8);
#pragma unroll
        for (int lt = 0; lt < 4; lt++)
            bfr[lt] = *(const short8*)&xs[(lt * 16 + c) * 264 + ks * 32 + g * 8];
#pragma unroll
        for (int jt = 0; jt < 3; jt++)
#pragma unroll
            for (int lt = 0; lt < 4; lt++)
                acc[jt][lt] = __builtin_amdgcn_mfma_f32_16x16x32_bf16(af[jt], bfr[lt], acc[jt][lt], 0, 0, 0);
    }
    __syncthreads();   // xs reads done; reuse for epilogue staging

    ushort* qs  = xs;                 // [64 l][72]  (h*8+dl)
    ushort* ksm = xs + 64 * 72;       // [64 l][72]
    ushort* vs  = xs + 2 * 64 * 72;   // [64 l][74]

#pragma unroll
    for (int jt = 0; jt < 3; jt++) {
#pragma unroll
        for (int r = 0; r < 4; r++) {
            int j = jbase + jt * 16 + g * 4 + r;
            float bias = b1[j];
            int t3 = j % 3, h = (j / 3) & 7, dl = (j / 24) & 7;
            int slot = h * 8 + dl;
#pragma unroll
            for (int lt = 0; lt < 4; lt++) {
                int l = lt * 16 + c;
                ushort u = f2bf(acc[jt][lt][r] + bias);
                if (t3 == 0)      qs[l * 72 + slot]  = u;
                else if (t3 == 1) ksm[l * 72 + slot] = u;
                else              vs[l * 74 + slot]  = u;
            }
        }
    }
    __syncthreads();

    // coalesced output
    {
        const int l = t & 63;
#pragma unroll
        for (int p = 0; p < 2; p++) {
            int h = p * 4 + (t >> 6);
            size_t rowq = (((size_t)(b * 8 + h) * 4 + dg) * LL + l0 + l) * 8;
            *(short8*)(qb + rowq) = *(const short8*)&qs[l * 72 + h * 8];
            *(short8*)(kb + rowq) = *(const short8*)&ksm[l * 72 + h * 8];
        }
#pragma unroll
        for (int p = 0; p < 16; p++) {
            int hd = p * 4 + (t >> 6);
            vt[((size_t)(b * 8 + (hd >> 3)) * HD + dg * 8 + (hd & 7)) * LL + l0 + l] = vs[l * 74 + hd];
        }
    }
}

// ---------------- Kernel 2: banded MFMA attention (band-only) ----------------
__global__ __launch_bounds__(256) void attn_kernel(const ushort* __restrict__ qb,
                                                   const ushort* __restrict__ kb,
                                                   const ushort* __restrict__ vt,
                                                   ushort* __restrict__ obuf) {
    __shared__ __align__(16) ushort pshare[4][640];  // per-wave 16 rows x 80 B
    const int it = blockIdx.x;
    const int bh = blockIdx.y;
    const int i0 = it * 64;
    const int t  = threadIdx.x;
    const int w  = t >> 6;
    const int ln = t & 63;
    const int c  = ln & 15;
    const int g  = ln >> 4;

    const size_t slab = ((size_t)bh * 4 + g) * LL;
    const int i = i0 + w * 16 + c;
    const bool iglob = (i == 0) | (i == 63) | (i == LL - 64) | (i == LL - 1);

    const short8 qf = *(const short8*)(qb + (slab + i) * 8);

    float4v o0 = {0.f, 0.f, 0.f, 0.f}, o1 = {0.f, 0.f, 0.f, 0.f};
    float dsum = 0.f;

    int t0, t1, ne = 0;
    int extra[4];
    t0 = it * 4 - 32; if (t0 < 0) t0 = 0;
    t1 = it * 4 + 35; if (t1 > 255) t1 = 255;
    const int gt[4] = {0, 3, 252, 255};
#pragma unroll
    for (int e = 0; e < 4; e++)
        if (gt[e] < t0 || gt[e] > t1) extra[ne++] = gt[e];
    const int nbt = t1 - t0 + 1;
    const int nt = nbt + ne;
    const int npair = (nt + 1) >> 1;

    ushort* wb = &pshare[w][0];
    const float scale = 0.17677669529663687f;
    const ushort* vb = vt + (size_t)bh * HD * LL;

    for (int m = 0; m < npair; m++) {
        const int n0 = 2 * m, n1 = 2 * m + 1;
        const int tA = (n0 < nbt) ? t0 + n0 : extra[n0 - nbt];
        const bool vBv = (n1 < nt);
        const int tB = (n1 < nbt) ? t0 + n1 : (vBv ? extra[n1 - nbt] : t0);

        const short8 kfA = *(const short8*)(kb + (slab + tA * 16 + c) * 8);
        const short8 kfB = *(const short8*)(kb + (slab + tB * 16 + c) * 8);
        float4v zero = {0.f, 0.f, 0.f, 0.f};
        float4v sA = __builtin_amdgcn_mfma_f32_16x16x32_bf16(kfA, qf, zero, 0, 0, 0);
        float4v sB = __builtin_amdgcn_mfma_f32_16x16x32_bf16(kfB, qf, zero, 0, 0, 0);

        float pA[4], pB[4];
#pragma unroll
        for (int r = 0; r < 4; r++) {
            int j = tA * 16 + g * 4 + r;
            bool band = (unsigned)(i - j + HALF_WIN) <= 2u * HALF_WIN;
            bool jg = (j == 0) | (j == 63) | (j == LL - 64) | (j == LL - 1);
            pA[r] = (band | jg | iglob) ? __expf(sA[r] * scale) : 0.f;
            dsum += pA[r];
        }
#pragma unroll
        for (int r = 0; r < 4; r++) {
            int j = tB * 16 + g * 4 + r;
            bool band = (unsigned)(i - j + HALF_WIN) <= 2u * HALF_WIN;
            bool jg = (j == 0) | (j == 63) | (j == LL - 64) | (j == LL - 1);
            pB[r] = (vBv & (band | jg | iglob)) ? __expf(sB[r] * scale) : 0.f;
            dsum += pB[r];
        }

        uint2 ua, ub2;
        ua.x  = (uint)f2bf(pA[0]) | ((uint)f2bf(pA[1]) << 16);
        ua.y  = (uint)f2bf(pA[2]) | ((uint)f2bf(pA[3]) << 16);
        ub2.x = (uint)f2bf(pB[0]) | ((uint)f2bf(pB[1]) << 16);
        ub2.y = (uint)f2bf(pB[2]) | ((uint)f2bf(pB[3]) << 16);
        *(uint2*)&wb[c * 40 + 4 * g]      = ua;
        *(uint2*)&wb[c * 40 + 16 + 4 * g] = ub2;

        const short8 pf = *(const short8*)&wb[c * 40 + 8 * g];

        const int jv = (g < 2) ? tA * 16 + g * 8 : tB * 16 + (g - 2) * 8;
        const short8 v0f = *(const short8*)(vb + (size_t)c * LL + jv);
        const short8 v1f = *(const short8*)(vb + (size_t)(16 + c) * LL + jv);
        o0 = __builtin_amdgcn_mfma_f32_16x16x32_bf16(pf, v0f, o0, 0, 0, 0);
        o1 = __builtin_amdgcn_mfma_f32_16x16x32_bf16(pf, v1f, o1, 0, 0, 0);
    }

    dsum += __shfl_xor(dsum, 16);
    dsum += __shfl_xor(dsum, 32);

    const int b = bh >> 3, hh = bh & 7;
#pragma unroll
    for (int r = 0; r < 4; r++) {
        float dn = __shfl(dsum, g * 4 + r);
        float inv = 1.0f / dn;
        int irow = i0 + w * 16 + g * 4 + r;
        size_t rowb = ((size_t)b * LL + irow) * CC;
        obuf[rowb + (size_t)c * 8 + hh]        = f2bf(o0[r] * inv);
        obuf[rowb + (size_t)(16 + c) * 8 + hh] = f2bf(o1[r] * inv);
    }
}

// ---------------- Kernel 2b: global rows, j-split partials -------------------
__global__ __launch_bounds__(256) void attn_global_partial(const ushort* __restrict__ qb,
                                                           const ushort* __restrict__ kb,
                                                           const ushort* __restrict__ vt,
                                                           float* __restrict__ gpart) {
    __shared__ float qs[4][32];
    __shared__ float sc[4][256];
    const int ch = blockIdx.x;
    const int bh = blockIdx.y;
    const int t  = threadIdx.x;
    const int gidx[4] = {0, 63, LL - 64, LL - 1};
    const float scale = 0.17677669529663687f;

    if (t < 128) {
        int r = t >> 5, dd = t & 31;
        int i = gidx[r];
        qs[r][dd] = ubf(qb[(((size_t)bh * 4 + (dd >> 3)) * LL + i) * 8 + (dd & 7)]);
    }
    __syncthreads();

    const int j = ch * 256 + t;
    float dot[4] = {};
#pragma unroll
    for (int s = 0; s < 4; s++) {
        const short8 kf = *(const short8*)(kb + (((size_t)bh * 4 + s) * LL + j) * 8);
#pragma unroll
        for (int e = 0; e < 8; e++) {
            float kv = ubf((ushort)kf[e]);
#pragma unroll
            for (int r = 0; r < 4; r++) dot[r] += qs[r][s * 8 + e] * kv;
        }
    }
#pragma unroll
    for (int r = 0; r < 4; r++) sc[r][t] = __expf(dot[r] * scale);
    __syncthreads();

    const int w = t >> 6, ln = t & 63;
    float den = sc[w][ln] + sc[w][ln + 64] + sc[w][ln + 128] + sc[w][ln + 192];
#pragma unroll
    for (int o = 1; o < 64; o <<= 1) den += __shfl_xor(den, o);

    const int dd = ln & 31, half = ln >> 5;
    float acc = 0.f;
    const ushort* vrow = vt + ((size_t)bh * HD + dd) * LL + ch * 256 + half * 128;
#pragma unroll
    for (int q8 = 0; q8 < 16; q8++) {
        const short8 v8 = *(const short8*)(vrow + q8 * 8);
#pragma unroll
        for (int e = 0; e < 8; e++) acc += sc[w][half * 128 + q8 * 8 + e] * ubf((ushort)v8[e]);
    }
    acc += __shfl_xor(acc, 32);

    float* gp = gpart + (((size_t)bh * 16 + ch) * 4 + w) * 33;
    if (ln < 32) gp[dd] = acc;
    if (ln == 0) gp[32] = den;
}

// ---------------- Kernel 2c: combine global-row partials ---------------------
__global__ __launch_bounds__(128) void attn_global_combine(const float* __restrict__ gpart,
                                                           ushort* __restrict__ obuf) {
    const int bh = blockIdx.x;
    const int t  = threadIdx.x;
    const int r  = t >> 5, dd = t & 31;
    const int gidx[4] = {0, 63, LL - 64, LL - 1};
    float pv = 0.f, den = 0.f;
#pragma unroll
    for (int ch = 0; ch < 16; ch++) {
        const float* gp = gpart + (((size_t)bh * 16 + ch) * 4 + r) * 33;
        pv  += gp[dd];
        den += gp[32];
    }
    const int b = bh >> 3, hh = bh & 7, i = gidx[r];
    obuf[((size_t)b * LL + i) * CC + dd * 8 + hh] = f2bf(pv / den);
}

// ---------------- Kernel 3: output projection (MFMA, zero-LDS) ---------------
__global__ __launch_bounds__(256) void proj_kernel(const ushort* __restrict__ obuf,
                                                   const ushort* __restrict__ w2t,
                                                   const float* __restrict__ b2,
                                                   float* __restrict__ out) {
    const int co0 = blockIdx.x * 16;
    const int l0  = blockIdx.y * 256 + (threadIdx.x >> 6) * 64;
    const int b   = blockIdx.z;
    const int ln  = threadIdx.x & 63;
    const int c   = ln & 15, g = ln >> 4;

    float4v acc[4] = {};
    const ushort* arow = w2t + (size_t)(co0 + c) * CC + g * 8;
    const ushort* brow = obuf + ((size_t)b * LL + l0 + c) * CC + g * 8;
#pragma unroll
    for (int ks = 0; ks < 8; ks++) {
        const short8 af = *(const short8*)(arow + ks * 32);
#pragma unroll
        for (int nf = 0; nf < 4; nf++) {
            const short8 bf = *(const short8*)(brow + (size_t)nf * 16 * CC + ks * 32);
            acc[nf] = __builtin_amdgcn_mfma_f32_16x16x32_bf16(af, bf, acc[nf], 0, 0, 0);
        }
    }
#pragma unroll
    for (int nf = 0; nf < 4; nf++) {
#pragma unroll
        for (int r = 0; r < 4; r++) {
            int co = co0 + g * 4 + r;
            int l  = l0 + nf * 16 + c;
            out[((size_t)b * CC + co) * LL + l] = acc[nf][r] + b2[co];
        }
    }
}

extern "C" void kernel_launch(void* const* d_in, const int* in_sizes, int n_in,
                              void* d_out, int out_size, void* d_ws, size_t ws_size,
                              hipStream_t stream) {
    const float* x  = (const float*)d_in[0];
    const float* w1 = (const float*)d_in[1];
    const float* b1 = (const float*)d_in[2];
    const float* w2 = (const float*)d_in[3];
    const float* b2 = (const float*)d_in[4];
    float* out = (float*)d_out;

    const size_t QKE = (size_t)BB * HEADS * LL * HD;  // 2,097,152 elems
    const size_t OBE = (size_t)BB * LL * CC;
    ushort* qb  = (ushort*)d_ws;
    ushort* kb  = qb + QKE;
    ushort* vt  = kb + QKE;
    ushort* ob  = vt + QKE;                // bf16 obuf [b][l][256]
    float*  gp  = (float*)(ob + OBE);      // [16][16][4][33]
    ushort* w2t = (ushort*)(gp + 16 * 16 * 4 * 33);
    ushort* w1t = w2t + CC * CC;           // [768][256]

    wt_kernel<<<dim3(16, 64), 256, 0, stream>>>(w1, w2, w1t, w2t);
    qkv_kernel<<<dim3(4, 64, 2), 256, 0, stream>>>(x, w1t, b1, qb, kb, vt);
    attn_kernel<<<dim3(64, 16), 256, 0, stream>>>(qb, kb, vt, ob);
    attn_global_partial<<<dim3(16, 16), 256, 0, stream>>>(qb, kb, vt, gp);
    attn_global_combine<<<dim3(16), 128, 0, stream>>>(gp, ob);
    proj_kernel<<<dim3(16, 16, 2), 256, 0, stream>>>(ob, w2t, b2, out);
}

// Round 7
// 145.086 us; speedup vs baseline: 14.2764x; 1.0236x over previous
//
#include <hip/hip_runtime.h>
#include <hip/hip_bf16.h>

#define BB 2
#define CC 256
#define HEADS 8
#define HD 32
#define LL 4096
#define HALF_WIN 512

using short8  = __attribute__((ext_vector_type(8))) short;
using float4v = __attribute__((ext_vector_type(4))) float;

__device__ __forceinline__ ushort f2bf(float x) {
    uint u = __float_as_uint(x);
    u += 0x7fff + ((u >> 16) & 1);
    return (ushort)(u >> 16);
}
__device__ __forceinline__ float ubf(ushort u) {
    return __uint_as_float((uint)u << 16);
}

// q is pre-scaled by (1/sqrt(32)) * log2(e) so attention uses exp2 directly
#define QSCALE 0.25503485f

// ---------------- Kernel 0: weight transpose + bf16 (w1 and w2) --------------
__global__ __launch_bounds__(256) void wt_kernel(const float* __restrict__ w1,
                                                 const float* __restrict__ w2,
                                                 ushort* __restrict__ w1t,
                                                 ushort* __restrict__ w2t) {
    __shared__ float tl[16][17];
    const int tx = threadIdx.x & 15, ty = threadIdx.x >> 4;
    const int ci0 = blockIdx.x * 16;
    const int y = blockIdx.y;
    if (y < 48) {
        int j0 = y * 16;
        tl[ty][tx] = w1[(size_t)(ci0 + ty) * 768 + j0 + tx];
        __syncthreads();
        w1t[(size_t)(j0 + ty) * CC + ci0 + tx] = f2bf(tl[tx][ty]);
    } else {
        int co0 = (y - 48) * 16;
        tl[ty][tx] = w2[(size_t)(ci0 + ty) * CC + co0 + tx];
        __syncthreads();
        w2t[(size_t)(co0 + ty) * CC + ci0 + tx] = f2bf(tl[tx][ty]);
    }
}

// ---------------- Kernel 1: QKV projection (MFMA) ----------------------------
__global__ __launch_bounds__(256) void qkv_kernel(const float* __restrict__ x,
                                                  const ushort* __restrict__ w1t,
                                                  const float* __restrict__ b1,
                                                  ushort* __restrict__ qb,
                                                  ushort* __restrict__ kb,
                                                  ushort* __restrict__ vt) {
    __shared__ __align__(16) ushort xs[64 * 264];  // [l][c]; reused in epilogue
    const int dg = blockIdx.x;
    const int l0 = blockIdx.y * 64;
    const int b  = blockIdx.z;
    const int t  = threadIdx.x;
    const int w  = t >> 6, ln = t & 63, c = ln & 15, g = ln >> 4;

    {
        const int l  = t & 63;
        const int cg = (t >> 6) * 4;
#pragma unroll
        for (int p = 0; p < 16; p++) {
            int c0 = p * 16 + cg;
            ushort4 v4;
            v4.x = f2bf(x[((size_t)b * CC + c0 + 0) * LL + l0 + l]);
            v4.y = f2bf(x[((size_t)b * CC + c0 + 1) * LL + l0 + l]);
            v4.z = f2bf(x[((size_t)b * CC + c0 + 2) * LL + l0 + l]);
            v4.w = f2bf(x[((size_t)b * CC + c0 + 3) * LL + l0 + l]);
            *(ushort4*)&xs[l * 264 + c0] = v4;
        }
    }
    __syncthreads();

    const int jbase = dg * 192 + w * 48;
    float4v acc[3][4] = {};
#pragma unroll
    for (int ks = 0; ks < 8; ks++) {
        short8 af[3], bfr[4];
#pragma unroll
        for (int jt = 0; jt < 3; jt++)
            af[jt] = *(const short8*)(w1t + (size_t)(jbase + jt * 16 + c) * CC + ks * 32 + g * 8);
#pragma unroll
        for (int lt = 0; lt < 4; lt++)
            bfr[lt] = *(const short8*)&xs[(lt * 16 + c) * 264 + ks * 32 + g * 8];
#pragma unroll
        for (int jt = 0; jt < 3; jt++)
#pragma unroll
            for (int lt = 0; lt < 4; lt++)
                acc[jt][lt] = __builtin_amdgcn_mfma_f32_16x16x32_bf16(af[jt], bfr[lt], acc[jt][lt], 0, 0, 0);
    }
    __syncthreads();

    ushort* qs  = xs;
    ushort* ksm = xs + 64 * 72;
    ushort* vs  = xs + 2 * 64 * 72;

#pragma unroll
    for (int jt = 0; jt < 3; jt++) {
#pragma unroll
        for (int r = 0; r < 4; r++) {
            int j = jbase + jt * 16 + g * 4 + r;
            float bias = b1[j];
            int t3 = j % 3, h = (j / 3) & 7, dl = (j / 24) & 7;
            int slot = h * 8 + dl;
#pragma unroll
            for (int lt = 0; lt < 4; lt++) {
                int l = lt * 16 + c;
                float val = acc[jt][lt][r] + bias;
                if (t3 == 0) val *= QSCALE;              // pre-scale q
                ushort u = f2bf(val);
                if (t3 == 0)      qs[l * 72 + slot]  = u;
                else if (t3 == 1) ksm[l * 72 + slot] = u;
                else              vs[l * 74 + slot]  = u;
            }
        }
    }
    __syncthreads();

    {
        const int l = t & 63;
#pragma unroll
        for (int p = 0; p < 2; p++) {
            int h = p * 4 + (t >> 6);
            size_t rowq = (((size_t)(b * 8 + h) * 4 + dg) * LL + l0 + l) * 8;
            *(short8*)(qb + rowq) = *(const short8*)&qs[l * 72 + h * 8];
            *(short8*)(kb + rowq) = *(const short8*)&ksm[l * 72 + h * 8];
        }
#pragma unroll
        for (int p = 0; p < 16; p++) {
            int hd = p * 4 + (t >> 6);
            vt[((size_t)(b * 8 + (hd >> 3)) * HD + dg * 8 + (hd & 7)) * LL + l0 + l] = vs[l * 74 + hd];
        }
    }
}

// ---------------- Kernel 2: banded MFMA attention ----------------------------
// 1D grid, XCD-swizzled: bh pair per XCD for L2 locality. Mask-free main loop
// over fully-in-band tiles (strength-reduced pointers); short masked epilogue
// for boundary + global-j tiles. Global ROWS are overwritten later -> no iglob.
__global__ __launch_bounds__(256) void attn_kernel(const ushort* __restrict__ qb,
                                                   const ushort* __restrict__ kb,
                                                   const ushort* __restrict__ vt,
                                                   ushort* __restrict__ obuf) {
    __shared__ __align__(16) ushort pshare[4][640];
    const int n  = blockIdx.x;
    const int bh = ((n & 7) << 1) | ((n >> 3) & 1);   // XCD = n%8 heuristic
    const int it = n >> 4;
    const int i0 = it * 64;
    const int t  = threadIdx.x;
    const int w  = t >> 6;
    const int ln = t & 63;
    const int c  = ln & 15;
    const int g  = ln >> 4;

    const size_t slab = ((size_t)bh * 4 + g) * LL;
    const int i = i0 + w * 16 + c;

    const short8 qf = *(const short8*)(qb + (slab + i) * 8);   // pre-scaled q

    float4v o0 = {0.f, 0.f, 0.f, 0.f}, o1 = {0.f, 0.f, 0.f, 0.f};
    float dsum = 0.f;

    int t0 = it * 4 - 32; if (t0 < 0) t0 = 0;
    int t1 = it * 4 + 35; if (t1 > 255) t1 = 255;
    int tf0 = it * 4 - 28; if (tf0 < 0) tf0 = 0;
    int tf1 = it * 4 + 31; if (tf1 > 255) tf1 = 255;
    // (tf1-tf0+1) is always even for i0 % 64 == 0

    int ml[12], nm = 0;
    for (int tt = t0; tt < tf0; tt++) ml[nm++] = tt;
    for (int tt = tf1 + 1; tt <= t1; tt++) ml[nm++] = tt;
    const int gt[4] = {0, 3, 252, 255};
#pragma unroll
    for (int e = 0; e < 4; e++)
        if (gt[e] < t0 || gt[e] > t1) ml[nm++] = gt[e];
    // nm is always even

    ushort* wb = &pshare[w][0];
    const ushort* vb = vt + (size_t)bh * HD * LL;

    // ---- main mask-free loop ----
    const int npair_f = (tf1 - tf0 + 1) >> 1;
    const ushort* kp  = kb + (slab + (size_t)(tf0 * 16 + c)) * 8;
    const ushort* vp0 = vb + (size_t)c * LL + tf0 * 16 + g * 8;
    const ushort* vp1 = vp0 + 16 * LL;
    for (int m = 0; m < npair_f; m++) {
        const short8 kfA = *(const short8*)kp;
        const short8 kfB = *(const short8*)(kp + 128);
        kp += 256;
        float4v zero = {0.f, 0.f, 0.f, 0.f};
        float4v sA = __builtin_amdgcn_mfma_f32_16x16x32_bf16(kfA, qf, zero, 0, 0, 0);
        float4v sB = __builtin_amdgcn_mfma_f32_16x16x32_bf16(kfB, qf, zero, 0, 0, 0);

        float pA[4], pB[4];
#pragma unroll
        for (int r = 0; r < 4; r++) { pA[r] = exp2f(sA[r]); dsum += pA[r]; }
#pragma unroll
        for (int r = 0; r < 4; r++) { pB[r] = exp2f(sB[r]); dsum += pB[r]; }

        uint2 ua, ub2;
        ua.x  = (uint)f2bf(pA[0]) | ((uint)f2bf(pA[1]) << 16);
        ua.y  = (uint)f2bf(pA[2]) | ((uint)f2bf(pA[3]) << 16);
        ub2.x = (uint)f2bf(pB[0]) | ((uint)f2bf(pB[1]) << 16);
        ub2.y = (uint)f2bf(pB[2]) | ((uint)f2bf(pB[3]) << 16);
        *(uint2*)&wb[c * 40 + 4 * g]      = ua;
        *(uint2*)&wb[c * 40 + 16 + 4 * g] = ub2;

        const short8 pf = *(const short8*)&wb[c * 40 + 8 * g];

        const short8 v0f = *(const short8*)vp0;
        const short8 v1f = *(const short8*)vp1;
        vp0 += 32; vp1 += 32;
        o0 = __builtin_amdgcn_mfma_f32_16x16x32_bf16(pf, v0f, o0, 0, 0, 0);
        o1 = __builtin_amdgcn_mfma_f32_16x16x32_bf16(pf, v1f, o1, 0, 0, 0);
    }

    // ---- masked epilogue (boundary + global-j tiles) ----
    for (int m = 0; m < nm; m += 2) {
        const int tA = ml[m], tB = ml[m + 1];
        const short8 kfA = *(const short8*)(kb + (slab + (size_t)(tA * 16 + c)) * 8);
        const short8 kfB = *(const short8*)(kb + (slab + (size_t)(tB * 16 + c)) * 8);
        float4v zero = {0.f, 0.f, 0.f, 0.f};
        float4v sA = __builtin_amdgcn_mfma_f32_16x16x32_bf16(kfA, qf, zero, 0, 0, 0);
        float4v sB = __builtin_amdgcn_mfma_f32_16x16x32_bf16(kfB, qf, zero, 0, 0, 0);

        float pA[4], pB[4];
#pragma unroll
        for (int r = 0; r < 4; r++) {
            int j = tA * 16 + g * 4 + r;
            bool band = (unsigned)(i - j + HALF_WIN) <= 2u * HALF_WIN;
            bool jg = (j == 0) | (j == 63) | (j == LL - 64) | (j == LL - 1);
            pA[r] = (band | jg) ? exp2f(sA[r]) : 0.f;
            dsum += pA[r];
        }
#pragma unroll
        for (int r = 0; r < 4; r++) {
            int j = tB * 16 + g * 4 + r;
            bool band = (unsigned)(i - j + HALF_WIN) <= 2u * HALF_WIN;
            bool jg = (j == 0) | (j == 63) | (j == LL - 64) | (j == LL - 1);
            pB[r] = (band | jg) ? exp2f(sB[r]) : 0.f;
            dsum += pB[r];
        }

        uint2 ua, ub2;
        ua.x  = (uint)f2bf(pA[0]) | ((uint)f2bf(pA[1]) << 16);
        ua.y  = (uint)f2bf(pA[2]) | ((uint)f2bf(pA[3]) << 16);
        ub2.x = (uint)f2bf(pB[0]) | ((uint)f2bf(pB[1]) << 16);
        ub2.y = (uint)f2bf(pB[2]) | ((uint)f2bf(pB[3]) << 16);
        *(uint2*)&wb[c * 40 + 4 * g]      = ua;
        *(uint2*)&wb[c * 40 + 16 + 4 * g] = ub2;

        const short8 pf = *(const short8*)&wb[c * 40 + 8 * g];

        const int jv = (g < 2) ? tA * 16 + g * 8 : tB * 16 + (g - 2) * 8;
        const short8 v0f = *(const short8*)(vb + (size_t)c * LL + jv);
        const short8 v1f = *(const short8*)(vb + (size_t)(16 + c) * LL + jv);
        o0 = __builtin_amdgcn_mfma_f32_16x16x32_bf16(pf, v0f, o0, 0, 0, 0);
        o1 = __builtin_amdgcn_mfma_f32_16x16x32_bf16(pf, v1f, o1, 0, 0, 0);
    }

    dsum += __shfl_xor(dsum, 16);
    dsum += __shfl_xor(dsum, 32);

    const int b = bh >> 3, hh = bh & 7;
#pragma unroll
    for (int r = 0; r < 4; r++) {
        float dn = __shfl(dsum, g * 4 + r);
        float inv = 1.0f / dn;
        int irow = i0 + w * 16 + g * 4 + r;
        size_t rowb = ((size_t)b * LL + irow) * CC;
        obuf[rowb + (size_t)c * 8 + hh]        = f2bf(o0[r] * inv);
        obuf[rowb + (size_t)(16 + c) * 8 + hh] = f2bf(o1[r] * inv);
    }
}

// ---------------- Kernel 2b: global rows, j-split partials -------------------
__global__ __launch_bounds__(256) void attn_global_partial(const ushort* __restrict__ qb,
                                                           const ushort* __restrict__ kb,
                                                           const ushort* __restrict__ vt,
                                                           float* __restrict__ gpart) {
    __shared__ float qs[4][32];
    __shared__ float sc[4][256];
    const int ch = blockIdx.x;
    const int bh = blockIdx.y;
    const int t  = threadIdx.x;
    const int gidx[4] = {0, 63, LL - 64, LL - 1};

    if (t < 128) {
        int r = t >> 5, dd = t & 31;
        int i = gidx[r];
        qs[r][dd] = ubf(qb[(((size_t)bh * 4 + (dd >> 3)) * LL + i) * 8 + (dd & 7)]);
    }
    __syncthreads();

    const int j = ch * 256 + t;
    float dot[4] = {};
#pragma unroll
    for (int s = 0; s < 4; s++) {
        const short8 kf = *(const short8*)(kb + (((size_t)bh * 4 + s) * LL + j) * 8);
#pragma unroll
        for (int e = 0; e < 8; e++) {
            float kv = ubf((ushort)kf[e]);
#pragma unroll
            for (int r = 0; r < 4; r++) dot[r] += qs[r][s * 8 + e] * kv;
        }
    }
#pragma unroll
    for (int r = 0; r < 4; r++) sc[r][t] = exp2f(dot[r]);   // q pre-scaled
    __syncthreads();

    const int w = t >> 6, ln = t & 63;
    float den = sc[w][ln] + sc[w][ln + 64] + sc[w][ln + 128] + sc[w][ln + 192];
#pragma unroll
    for (int o = 1; o < 64; o <<= 1) den += __shfl_xor(den, o);

    const int dd = ln & 31, half = ln >> 5;
    float acc = 0.f;
    const ushort* vrow = vt + ((size_t)bh * HD + dd) * LL + ch * 256 + half * 128;
#pragma unroll
    for (int q8 = 0; q8 < 16; q8++) {
        const short8 v8 = *(const short8*)(vrow + q8 * 8);
#pragma unroll
        for (int e = 0; e < 8; e++) acc += sc[w][half * 128 + q8 * 8 + e] * ubf((ushort)v8[e]);
    }
    acc += __shfl_xor(acc, 32);

    float* gp = gpart + (((size_t)bh * 16 + ch) * 4 + w) * 33;
    if (ln < 32) gp[dd] = acc;
    if (ln == 0) gp[32] = den;
}

// ---------------- Kernel 2c: combine global-row partials ---------------------
__global__ __launch_bounds__(128) void attn_global_combine(const float* __restrict__ gpart,
                                                           ushort* __restrict__ obuf) {
    const int bh = blockIdx.x;
    const int t  = threadIdx.x;
    const int r  = t >> 5, dd = t & 31;
    const int gidx[4] = {0, 63, LL - 64, LL - 1};
    float pv = 0.f, den = 0.f;
#pragma unroll
    for (int ch = 0; ch < 16; ch++) {
        const float* gp = gpart + (((size_t)bh * 16 + ch) * 4 + r) * 33;
        pv  += gp[dd];
        den += gp[32];
    }
    const int b = bh >> 3, hh = bh & 7, i = gidx[r];
    obuf[((size_t)b * LL + i) * CC + dd * 8 + hh] = f2bf(pv / den);
}

// ---------------- Kernel 3: output projection (MFMA, zero-LDS) ---------------
__global__ __launch_bounds__(256) void proj_kernel(const ushort* __restrict__ obuf,
                                                   const ushort* __restrict__ w2t,
                                                   const float* __restrict__ b2,
                                                   float* __restrict__ out) {
    const int co0 = blockIdx.x * 16;
    const int l0  = blockIdx.y * 256 + (threadIdx.x >> 6) * 64;
    const int b   = blockIdx.z;
    const int ln  = threadIdx.x & 63;
    const int c   = ln & 15, g = ln >> 4;

    float4v acc[4] = {};
    const ushort* arow = w2t + (size_t)(co0 + c) * CC + g * 8;
    const ushort* brow = obuf + ((size_t)b * LL + l0 + c) * CC + g * 8;
#pragma unroll
    for (int ks = 0; ks < 8; ks++) {
        const short8 af = *(const short8*)(arow + ks * 32);
#pragma unroll
        for (int nf = 0; nf < 4; nf++) {
            const short8 bf = *(const short8*)(brow + (size_t)nf * 16 * CC + ks * 32);
            acc[nf] = __builtin_amdgcn_mfma_f32_16x16x32_bf16(af, bf, acc[nf], 0, 0, 0);
        }
    }
#pragma unroll
    for (int nf = 0; nf < 4; nf++) {
#pragma unroll
        for (int r = 0; r < 4; r++) {
            int co = co0 + g * 4 + r;
            int l  = l0 + nf * 16 + c;
            out[((size_t)b * CC + co) * LL + l] = acc[nf][r] + b2[co];
        }
    }
}

extern "C" void kernel_launch(void* const* d_in, const int* in_sizes, int n_in,
                              void* d_out, int out_size, void* d_ws, size_t ws_size,
                              hipStream_t stream) {
    const float* x  = (const float*)d_in[0];
    const float* w1 = (const float*)d_in[1];
    const float* b1 = (const float*)d_in[2];
    const float* w2 = (const float*)d_in[3];
    const float* b2 = (const float*)d_in[4];
    float* out = (float*)d_out;

    const size_t QKE = (size_t)BB * HEADS * LL * HD;
    const size_t OBE = (size_t)BB * LL * CC;
    ushort* qb  = (ushort*)d_ws;
    ushort* kb  = qb + QKE;
    ushort* vt  = kb + QKE;
    ushort* ob  = vt + QKE;
    float*  gp  = (float*)(ob + OBE);
    ushort* w2t = (ushort*)(gp + 16 * 16 * 4 * 33);
    ushort* w1t = w2t + CC * CC;

    wt_kernel<<<dim3(16, 64), 256, 0, stream>>>(w1, w2, w1t, w2t);
    qkv_kernel<<<dim3(4, 64, 2), 256, 0, stream>>>(x, w1t, b1, qb, kb, vt);
    attn_kernel<<<dim3(1024), 256, 0, stream>>>(qb, kb, vt, ob);
    attn_global_partial<<<dim3(16, 16), 256, 0, stream>>>(qb, kb, vt, gp);
    attn_global_combine<<<dim3(16), 128, 0, stream>>>(gp, ob);
    proj_kernel<<<dim3(16, 16, 2), 256, 0, stream>>>(ob, w2t, b2, out);
}

// Round 8
// 144.761 us; speedup vs baseline: 14.3085x; 1.0022x over previous
//
#include <hip/hip_runtime.h>
#include <hip/hip_bf16.h>

#define BB 2
#define CC 256
#define HEADS 8
#define HD 32
#define LL 4096
#define HALF_WIN 512

using short8  = __attribute__((ext_vector_type(8))) short;
using short4v = __attribute__((ext_vector_type(4))) short;
using float4v = __attribute__((ext_vector_type(4))) float;

__device__ __forceinline__ ushort f2bf(float x) {
    uint u = __float_as_uint(x);
    u += 0x7fff + ((u >> 16) & 1);
    return (ushort)(u >> 16);
}
__device__ __forceinline__ float ubf(ushort u) {
    return __uint_as_float((uint)u << 16);
}
// packed f32x2 -> bf16x2 (lo = first arg), HW instr on gfx950
__device__ __forceinline__ uint pk2bf(float a, float b) {
#if __has_builtin(__builtin_amdgcn_cvt_pk_bf16_f32)
    typedef __bf16 v2bf __attribute__((ext_vector_type(2)));
    union { v2bf v; uint u; } cv;
    cv.v = __builtin_amdgcn_cvt_pk_bf16_f32(a, b);
    return cv.u;
#else
    return (uint)f2bf(a) | ((uint)f2bf(b) << 16);
#endif
}

// q is pre-scaled by (1/sqrt(32)) * log2(e) so attention uses exp2 directly
#define QSCALE 0.25503485f

// ---------------- Kernel 0: weight transpose + bf16 (w1 and w2) --------------
__global__ __launch_bounds__(256) void wt_kernel(const float* __restrict__ w1,
                                                 const float* __restrict__ w2,
                                                 ushort* __restrict__ w1t,
                                                 ushort* __restrict__ w2t) {
    __shared__ float tl[16][17];
    const int tx = threadIdx.x & 15, ty = threadIdx.x >> 4;
    const int ci0 = blockIdx.x * 16;
    const int y = blockIdx.y;
    if (y < 48) {
        int j0 = y * 16;
        tl[ty][tx] = w1[(size_t)(ci0 + ty) * 768 + j0 + tx];
        __syncthreads();
        w1t[(size_t)(j0 + ty) * CC + ci0 + tx] = f2bf(tl[tx][ty]);
    } else {
        int co0 = (y - 48) * 16;
        tl[ty][tx] = w2[(size_t)(ci0 + ty) * CC + co0 + tx];
        __syncthreads();
        w2t[(size_t)(co0 + ty) * CC + ci0 + tx] = f2bf(tl[tx][ty]);
    }
}

// ---------------- Kernel 1: QKV projection (MFMA) ----------------------------
__global__ __launch_bounds__(256) void qkv_kernel(const float* __restrict__ x,
                                                  const ushort* __restrict__ w1t,
                                                  const float* __restrict__ b1,
                                                  ushort* __restrict__ qb,
                                                  ushort* __restrict__ kb,
                                                  ushort* __restrict__ vt) {
    __shared__ __align__(16) ushort xs[64 * 264];  // [l][c]; reused in epilogue
    const int dg = blockIdx.x;
    const int l0 = blockIdx.y * 64;
    const int b  = blockIdx.z;
    const int t  = threadIdx.x;
    const int w  = t >> 6, ln = t & 63, c = ln & 15, g = ln >> 4;

    {
        const int l  = t & 63;
        const int cg = (t >> 6) * 4;
#pragma unroll
        for (int p = 0; p < 16; p++) {
            int c0 = p * 16 + cg;
            float a0 = x[((size_t)b * CC + c0 + 0) * LL + l0 + l];
            float a1 = x[((size_t)b * CC + c0 + 1) * LL + l0 + l];
            float a2 = x[((size_t)b * CC + c0 + 2) * LL + l0 + l];
            float a3 = x[((size_t)b * CC + c0 + 3) * LL + l0 + l];
            uint2 u;
            u.x = pk2bf(a0, a1);
            u.y = pk2bf(a2, a3);
            *(uint2*)&xs[l * 264 + c0] = u;
        }
    }
    __syncthreads();

    const int jbase = dg * 192 + w * 48;
    float4v acc[3][4] = {};
#pragma unroll
    for (int ks = 0; ks < 8; ks++) {
        short8 af[3], bfr[4];
#pragma unroll
        for (int jt = 0; jt < 3; jt++)
            af[jt] = *(const short8*)(w1t + (size_t)(jbase + jt * 16 + c) * CC + ks * 32 + g * 8);
#pragma unroll
        for (int lt = 0; lt < 4; lt++)
            bfr[lt] = *(const short8*)&xs[(lt * 16 + c) * 264 + ks * 32 + g * 8];
#pragma unroll
        for (int jt = 0; jt < 3; jt++)
#pragma unroll
            for (int lt = 0; lt < 4; lt++)
                acc[jt][lt] = __builtin_amdgcn_mfma_f32_16x16x32_bf16(af[jt], bfr[lt], acc[jt][lt], 0, 0, 0);
    }
    __syncthreads();

    ushort* qs  = xs;
    ushort* ksm = xs + 64 * 72;
    ushort* vs  = xs + 2 * 64 * 72;

#pragma unroll
    for (int jt = 0; jt < 3; jt++) {
#pragma unroll
        for (int r = 0; r < 4; r++) {
            int j = jbase + jt * 16 + g * 4 + r;
            float bias = b1[j];
            int t3 = j % 3, h = (j / 3) & 7, dl = (j / 24) & 7;
            int slot = h * 8 + dl;
            float v0 = acc[jt][0][r] + bias;
            float v1 = acc[jt][1][r] + bias;
            float v2 = acc[jt][2][r] + bias;
            float v3 = acc[jt][3][r] + bias;
            if (t3 == 0) { v0 *= QSCALE; v1 *= QSCALE; v2 *= QSCALE; v3 *= QSCALE; }
            uint u01 = pk2bf(v0, v1);
            uint u23 = pk2bf(v2, v3);
            ushort* dst = (t3 == 0) ? qs : (t3 == 1) ? ksm : vs;
            int stride = (t3 == 2) ? 74 : 72;
            dst[(0 * 16 + c) * stride + slot] = (ushort)u01;
            dst[(1 * 16 + c) * stride + slot] = (ushort)(u01 >> 16);
            dst[(2 * 16 + c) * stride + slot] = (ushort)u23;
            dst[(3 * 16 + c) * stride + slot] = (ushort)(u23 >> 16);
        }
    }
    __syncthreads();

    {
        const int l = t & 63;
#pragma unroll
        for (int p = 0; p < 2; p++) {
            int h = p * 4 + (t >> 6);
            size_t rowq = (((size_t)(b * 8 + h) * 4 + dg) * LL + l0 + l) * 8;
            *(short8*)(qb + rowq) = *(const short8*)&qs[l * 72 + h * 8];
            *(short8*)(kb + rowq) = *(const short8*)&ksm[l * 72 + h * 8];
        }
#pragma unroll
        for (int p = 0; p < 16; p++) {
            int hd = p * 4 + (t >> 6);
            vt[((size_t)(b * 8 + (hd >> 3)) * HD + dg * 8 + (hd & 7)) * LL + l0 + l] = vs[l * 74 + hd];
        }
    }
}

__device__ __forceinline__ int gcol_of(int tt) {
    return (tt == 0) ? 0 : (tt == 3) ? 63 : (tt == 252) ? LL - 64 : (tt == 255) ? LL - 1 : -1;
}

// ---------------- Kernel 2: banded MFMA attention ----------------------------
__global__ __launch_bounds__(256) void attn_kernel(const ushort* __restrict__ qb,
                                                   const ushort* __restrict__ kb,
                                                   const ushort* __restrict__ vt,
                                                   ushort* __restrict__ obuf) {
    __shared__ __align__(16) ushort pshare[4][576];  // per-wave 16 rows x 72 B (bank-clean)
    const int n  = blockIdx.x;
    const int bh = ((n & 7) << 1) | ((n >> 3) & 1);   // XCD = n%8 heuristic
    const int it = n >> 4;
    const int i0 = it * 64;
    const int t  = threadIdx.x;
    const int w  = t >> 6;
    const int ln = t & 63;
    const int c  = ln & 15;
    const int g  = ln >> 4;

    const size_t slab = ((size_t)bh * 4 + g) * LL;
    const int i = i0 + w * 16 + c;

    const short8 qf = *(const short8*)(qb + (slab + i) * 8);   // pre-scaled q

    float4v o0 = {0.f, 0.f, 0.f, 0.f}, o1 = {0.f, 0.f, 0.f, 0.f};
    float dsum = 0.f;

    int t0 = it * 4 - 32; if (t0 < 0) t0 = 0;
    int t1 = it * 4 + 35; if (t1 > 255) t1 = 255;
    int tf0 = it * 4 - 28; if (tf0 < 0) tf0 = 0;
    int tf1 = it * 4 + 31; if (tf1 > 255) tf1 = 255;

    int ml[12], nm = 0;
    for (int tt = t0; tt < tf0; tt++) ml[nm++] = tt;
    for (int tt = tf1 + 1; tt <= t1; tt++) ml[nm++] = tt;
    const int gt[4] = {0, 3, 252, 255};
#pragma unroll
    for (int e = 0; e < 4; e++)
        if (gt[e] < t0 || gt[e] > t1) ml[nm++] = gt[e];

    ushort* wb = &pshare[w][0];
    const ushort* vb = vt + (size_t)bh * HD * LL;

    // ---- main mask-free loop ----
    const int npair_f = (tf1 - tf0 + 1) >> 1;
    const ushort* kp  = kb + (slab + (size_t)(tf0 * 16 + c)) * 8;
    const ushort* vp0 = vb + (size_t)c * LL + tf0 * 16 + g * 8;
    const ushort* vp1 = vp0 + 16 * LL;
    for (int m = 0; m < npair_f; m++) {
        const short8 kfA = *(const short8*)kp;
        const short8 kfB = *(const short8*)(kp + 128);
        kp += 256;
        float4v zero = {0.f, 0.f, 0.f, 0.f};
        float4v sA = __builtin_amdgcn_mfma_f32_16x16x32_bf16(kfA, qf, zero, 0, 0, 0);
        float4v sB = __builtin_amdgcn_mfma_f32_16x16x32_bf16(kfB, qf, zero, 0, 0, 0);

        float pA[4], pB[4];
#pragma unroll
        for (int r = 0; r < 4; r++) { pA[r] = exp2f(sA[r]); dsum += pA[r]; }
#pragma unroll
        for (int r = 0; r < 4; r++) { pB[r] = exp2f(sB[r]); dsum += pB[r]; }

        uint2 ua, ub2;
        ua.x  = pk2bf(pA[0], pA[1]);
        ua.y  = pk2bf(pA[2], pA[3]);
        ub2.x = pk2bf(pB[0], pB[1]);
        ub2.y = pk2bf(pB[2], pB[3]);
        *(uint2*)&wb[c * 36 + 4 * g]      = ua;
        *(uint2*)&wb[c * 36 + 16 + 4 * g] = ub2;

        union { short8 s8; short4v s4[2]; } pu;
        pu.s4[0] = *(const short4v*)&wb[c * 36 + 8 * g];
        pu.s4[1] = *(const short4v*)&wb[c * 36 + 8 * g + 4];
        const short8 pf = pu.s8;

        const short8 v0f = *(const short8*)vp0;
        const short8 v1f = *(const short8*)vp1;
        vp0 += 32; vp1 += 32;
        o0 = __builtin_amdgcn_mfma_f32_16x16x32_bf16(pf, v0f, o0, 0, 0, 0);
        o1 = __builtin_amdgcn_mfma_f32_16x16x32_bf16(pf, v1f, o1, 0, 0, 0);
    }

    // ---- masked epilogue (boundary + global-j tiles) ----
    for (int m = 0; m < nm; m += 2) {
        const int tA = ml[m], tB = ml[m + 1];
        const int gA = gcol_of(tA), gB = gcol_of(tB);
        const short8 kfA = *(const short8*)(kb + (slab + (size_t)(tA * 16 + c)) * 8);
        const short8 kfB = *(const short8*)(kb + (slab + (size_t)(tB * 16 + c)) * 8);
        float4v zero = {0.f, 0.f, 0.f, 0.f};
        float4v sA = __builtin_amdgcn_mfma_f32_16x16x32_bf16(kfA, qf, zero, 0, 0, 0);
        float4v sB = __builtin_amdgcn_mfma_f32_16x16x32_bf16(kfB, qf, zero, 0, 0, 0);

        float pA[4], pB[4];
#pragma unroll
        for (int r = 0; r < 4; r++) {
            int j = tA * 16 + g * 4 + r;
            bool ok = ((unsigned)(i - j + HALF_WIN) <= 2u * HALF_WIN) | (j == gA);
            pA[r] = ok ? exp2f(sA[r]) : 0.f;
            dsum += pA[r];
        }
#pragma unroll
        for (int r = 0; r < 4; r++) {
            int j = tB * 16 + g * 4 + r;
            bool ok = ((unsigned)(i - j + HALF_WIN) <= 2u * HALF_WIN) | (j == gB);
            pB[r] = ok ? exp2f(sB[r]) : 0.f;
            dsum += pB[r];
        }

        uint2 ua, ub2;
        ua.x  = pk2bf(pA[0], pA[1]);
        ua.y  = pk2bf(pA[2], pA[3]);
        ub2.x = pk2bf(pB[0], pB[1]);
        ub2.y = pk2bf(pB[2], pB[3]);
        *(uint2*)&wb[c * 36 + 4 * g]      = ua;
        *(uint2*)&wb[c * 36 + 16 + 4 * g] = ub2;

        union { short8 s8; short4v s4[2]; } pu;
        pu.s4[0] = *(const short4v*)&wb[c * 36 + 8 * g];
        pu.s4[1] = *(const short4v*)&wb[c * 36 + 8 * g + 4];
        const short8 pf = pu.s8;

        const int jv = (g < 2) ? tA * 16 + g * 8 : tB * 16 + (g - 2) * 8;
        const short8 v0f = *(const short8*)(vb + (size_t)c * LL + jv);
        const short8 v1f = *(const short8*)(vb + (size_t)(16 + c) * LL + jv);
        o0 = __builtin_amdgcn_mfma_f32_16x16x32_bf16(pf, v0f, o0, 0, 0, 0);
        o1 = __builtin_amdgcn_mfma_f32_16x16x32_bf16(pf, v1f, o1, 0, 0, 0);
    }

    dsum += __shfl_xor(dsum, 16);
    dsum += __shfl_xor(dsum, 32);

    const int b = bh >> 3, hh = bh & 7;
#pragma unroll
    for (int r = 0; r < 4; r++) {
        float dn = __shfl(dsum, g * 4 + r);
        float inv = 1.0f / dn;
        int irow = i0 + w * 16 + g * 4 + r;
        size_t rowb = ((size_t)b * LL + irow) * CC;
        obuf[rowb + (size_t)c * 8 + hh]        = f2bf(o0[r] * inv);
        obuf[rowb + (size_t)(16 + c) * 8 + hh] = f2bf(o1[r] * inv);
    }
}

// ---------------- Kernel 2b: global rows, j-split partials -------------------
__global__ __launch_bounds__(256) void attn_global_partial(const ushort* __restrict__ qb,
                                                           const ushort* __restrict__ kb,
                                                           const ushort* __restrict__ vt,
                                                           float* __restrict__ gpart) {
    __shared__ float qs[4][32];
    __shared__ float sc[4][256];
    const int ch = blockIdx.x;
    const int bh = blockIdx.y;
    const int t  = threadIdx.x;
    const int gidx[4] = {0, 63, LL - 64, LL - 1};

    if (t < 128) {
        int r = t >> 5, dd = t & 31;
        int i = gidx[r];
        qs[r][dd] = ubf(qb[(((size_t)bh * 4 + (dd >> 3)) * LL + i) * 8 + (dd & 7)]);
    }
    __syncthreads();

    const int j = ch * 256 + t;
    float dot[4] = {};
#pragma unroll
    for (int s = 0; s < 4; s++) {
        const short8 kf = *(const short8*)(kb + (((size_t)bh * 4 + s) * LL + j) * 8);
#pragma unroll
        for (int e = 0; e < 8; e++) {
            float kv = ubf((ushort)kf[e]);
#pragma unroll
            for (int r = 0; r < 4; r++) dot[r] += qs[r][s * 8 + e] * kv;
        }
    }
#pragma unroll
    for (int r = 0; r < 4; r++) sc[r][t] = exp2f(dot[r]);   // q pre-scaled
    __syncthreads();

    const int w = t >> 6, ln = t & 63;
    float den = sc[w][ln] + sc[w][ln + 64] + sc[w][ln + 128] + sc[w][ln + 192];
#pragma unroll
    for (int o = 1; o < 64; o <<= 1) den += __shfl_xor(den, o);

    const int dd = ln & 31, half = ln >> 5;
    float acc = 0.f;
    const ushort* vrow = vt + ((size_t)bh * HD + dd) * LL + ch * 256 + half * 128;
#pragma unroll
    for (int q8 = 0; q8 < 16; q8++) {
        const short8 v8 = *(const short8*)(vrow + q8 * 8);
#pragma unroll
        for (int e = 0; e < 8; e++) acc += sc[w][half * 128 + q8 * 8 + e] * ubf((ushort)v8[e]);
    }
    acc += __shfl_xor(acc, 32);

    float* gp = gpart + (((size_t)bh * 16 + ch) * 4 + w) * 33;
    if (ln < 32) gp[dd] = acc;
    if (ln == 0) gp[32] = den;
}

// ---------------- Kernel 2c: combine global-row partials ---------------------
__global__ __launch_bounds__(128) void attn_global_combine(const float* __restrict__ gpart,
                                                           ushort* __restrict__ obuf) {
    const int bh = blockIdx.x;
    const int t  = threadIdx.x;
    const int r  = t >> 5, dd = t & 31;
    const int gidx[4] = {0, 63, LL - 64, LL - 1};
    float pv = 0.f, den = 0.f;
#pragma unroll
    for (int ch = 0; ch < 16; ch++) {
        const float* gp = gpart + (((size_t)bh * 16 + ch) * 4 + r) * 33;
        pv  += gp[dd];
        den += gp[32];
    }
    const int b = bh >> 3, hh = bh & 7, i = gidx[r];
    obuf[((size_t)b * LL + i) * CC + dd * 8 + hh] = f2bf(pv / den);
}

// ---------------- Kernel 3: output projection (MFMA, zero-LDS) ---------------
__global__ __launch_bounds__(256) void proj_kernel(const ushort* __restrict__ obuf,
                                                   const ushort* __restrict__ w2t,
                                                   const float* __restrict__ b2,
                                                   float* __restrict__ out) {
    const int co0 = blockIdx.x * 16;
    const int l0  = blockIdx.y * 256 + (threadIdx.x >> 6) * 64;
    const int b   = blockIdx.z;
    const int ln  = threadIdx.x & 63;
    const int c   = ln & 15, g = ln >> 4;

    float4v acc[4] = {};
    const ushort* arow = w2t + (size_t)(co0 + c) * CC + g * 8;
    const ushort* brow = obuf + ((size_t)b * LL + l0 + c) * CC + g * 8;
#pragma unroll
    for (int ks = 0; ks < 8; ks++) {
        const short8 af = *(const short8*)(arow + ks * 32);
#pragma unroll
        for (int nf = 0; nf < 4; nf++) {
            const short8 bf = *(const short8*)(brow + (size_t)nf * 16 * CC + ks * 32);
            acc[nf] = __builtin_amdgcn_mfma_f32_16x16x32_bf16(af, bf, acc[nf], 0, 0, 0);
        }
    }
#pragma unroll
    for (int nf = 0; nf < 4; nf++) {
#pragma unroll
        for (int r = 0; r < 4; r++) {
            int co = co0 + g * 4 + r;
            int l  = l0 + nf * 16 + c;
            out[((size_t)b * CC + co) * LL + l] = acc[nf][r] + b2[co];
        }
    }
}

extern "C" void kernel_launch(void* const* d_in, const int* in_sizes, int n_in,
                              void* d_out, int out_size, void* d_ws, size_t ws_size,
                              hipStream_t stream) {
    const float* x  = (const float*)d_in[0];
    const float* w1 = (const float*)d_in[1];
    const float* b1 = (const float*)d_in[2];
    const float* w2 = (const float*)d_in[3];
    const float* b2 = (const float*)d_in[4];
    float* out = (float*)d_out;

    const size_t QKE = (size_t)BB * HEADS * LL * HD;
    const size_t OBE = (size_t)BB * LL * CC;
    ushort* qb  = (ushort*)d_ws;
    ushort* kb  = qb + QKE;
    ushort* vt  = kb + QKE;
    ushort* ob  = vt + QKE;
    float*  gp  = (float*)(ob + OBE);
    ushort* w2t = (ushort*)(gp + 16 * 16 * 4 * 33);
    ushort* w1t = w2t + CC * CC;

    wt_kernel<<<dim3(16, 64), 256, 0, stream>>>(w1, w2, w1t, w2t);
    qkv_kernel<<<dim3(4, 64, 2), 256, 0, stream>>>(x, w1t, b1, qb, kb, vt);
    attn_kernel<<<dim3(1024), 256, 0, stream>>>(qb, kb, vt, ob);
    attn_global_partial<<<dim3(16, 16), 256, 0, stream>>>(qb, kb, vt, gp);
    attn_global_combine<<<dim3(16), 128, 0, stream>>>(gp, ob);
    proj_kernel<<<dim3(16, 16, 2), 256, 0, stream>>>(ob, w2t, b2, out);
}